// Round 1
// baseline (615.261 us; speedup 1.0000x reference)
//
#include <hip/hip_runtime.h>
#include <hip/hip_bf16.h>

#define B_ 8
#define N_ 8192
#define D_ 512
#define M_ 64   // MAX_NODES == NODE_DIM == SCORE_HIDDEN == 64

// ---------------------------------------------------------------------------
// K1: scores = relu(X@W1 + b1) @ w2 + b2      X:[65536,512] W1:[512,64]
// tile: 128 tokens x 64 hidden, 256 threads, 8x4 register block
// ---------------------------------------------------------------------------
__global__ __launch_bounds__(256, 3) void k_scores(
    const float* __restrict__ X, const float* __restrict__ W1,
    const float* __restrict__ b1, const float* __restrict__ w2,
    const float* __restrict__ b2, float* __restrict__ scores)
{
  __shared__ __align__(16) float sXT[64][132];  // [k][token], padded (132%4==0)
  __shared__ __align__(16) float sW [64][68];   // [k][hidden]
  const int tid  = threadIdx.x;
  const int row0 = blockIdx.x * 128;
  const int tx = tid & 15;   // hidden group: cols tx*4..tx*4+3
  const int ty = tid >> 4;   // token group: rows ty*8..ty*8+7

  float acc[8][4];
  #pragma unroll
  for (int i = 0; i < 8; ++i)
    #pragma unroll
    for (int j = 0; j < 4; ++j) acc[i][j] = 0.f;

  for (int kk = 0; kk < 8; ++kk) {
    const int k0 = kk * 64;
    __syncthreads();
    {
      const int r = tid >> 4, c4 = tid & 15;
      #pragma unroll
      for (int p = 0; p < 4; ++p) {
        float4 w = *(const float4*)(W1 + (size_t)(k0 + r + p * 16) * 64 + c4 * 4);
        *(float4*)&sW[r + p * 16][c4 * 4] = w;
      }
      #pragma unroll
      for (int p = 0; p < 8; ++p) {
        const int tt = r + p * 16;
        float4 v = *(const float4*)(X + (size_t)(row0 + tt) * D_ + k0 + c4 * 4);
        sXT[c4 * 4 + 0][tt] = v.x;
        sXT[c4 * 4 + 1][tt] = v.y;
        sXT[c4 * 4 + 2][tt] = v.z;
        sXT[c4 * 4 + 3][tt] = v.w;
      }
    }
    __syncthreads();
    #pragma unroll 8
    for (int k = 0; k < 64; ++k) {
      const float4 a0 = *(const float4*)&sXT[k][ty * 8];
      const float4 a1 = *(const float4*)&sXT[k][ty * 8 + 4];
      const float4 bq = *(const float4*)&sW[k][tx * 4];
      const float av[8] = {a0.x, a0.y, a0.z, a0.w, a1.x, a1.y, a1.z, a1.w};
      const float bv[4] = {bq.x, bq.y, bq.z, bq.w};
      #pragma unroll
      for (int i = 0; i < 8; ++i)
        #pragma unroll
        for (int j = 0; j < 4; ++j) acc[i][j] = fmaf(av[i], bv[j], acc[i][j]);
    }
  }
  float b1v[4], w2v[4];
  #pragma unroll
  for (int j = 0; j < 4; ++j) { b1v[j] = b1[tx * 4 + j]; w2v[j] = w2[tx * 4 + j]; }
  const float b2v = b2[0];
  #pragma unroll
  for (int i = 0; i < 8; ++i) {
    float p = 0.f;
    #pragma unroll
    for (int j = 0; j < 4; ++j) {
      float h = fmaxf(acc[i][j] + b1v[j], 0.f);
      p = fmaf(h, w2v[j], p);
    }
    #pragma unroll
    for (int off = 1; off < 16; off <<= 1) p += __shfl_xor(p, off, 16);
    if (tx == 0) scores[row0 + ty * 8 + i] = p + b2v;
  }
}

// ---------------------------------------------------------------------------
// K2: per-batch stats (mean/std/count -> take_k) + iterative top-64 from LDS
// ---------------------------------------------------------------------------
__global__ __launch_bounds__(256) void k_select(
    const float* __restrict__ scores, int* __restrict__ top_idx,
    int* __restrict__ take_k)
{
  __shared__ float sS[N_];
  __shared__ float red[256];
  __shared__ int   redi[256];
  __shared__ float sThr;
  const int b = blockIdx.x, tid = threadIdx.x;
  const float* s = scores + (size_t)b * N_;
  float sum = 0.f, sq = 0.f;
  for (int i = tid; i < N_; i += 256) {
    float v = s[i]; sS[i] = v; sum += v; sq = fmaf(v, v, sq);
  }
  red[tid] = sum; __syncthreads();
  for (int st = 128; st > 0; st >>= 1) { if (tid < st) red[tid] += red[tid + st]; __syncthreads(); }
  const float tot = red[0]; __syncthreads();
  red[tid] = sq; __syncthreads();
  for (int st = 128; st > 0; st >>= 1) { if (tid < st) red[tid] += red[tid + st]; __syncthreads(); }
  if (tid == 0) {
    const float mean = tot / (float)N_;
    const float var  = red[0] / (float)N_ - mean * mean;
    sThr = mean + 0.5f * sqrtf(fmaxf(var, 0.f));
  }
  __syncthreads();
  const float thr = sThr;
  int c = 0;
  for (int i = tid; i < N_; i += 256) c += (sS[i] > thr) ? 1 : 0;
  redi[tid] = c; __syncthreads();
  for (int st = 128; st > 0; st >>= 1) { if (tid < st) redi[tid] += redi[tid + st]; __syncthreads(); }
  if (tid == 0) {
    const int cnt = redi[0];  // fallback_k = min(64, max(4, 8192/16)) = 64
    take_k[b] = (cnt == 0) ? M_ : (cnt < M_ ? cnt : M_);
  }
  __syncthreads();
  for (int it = 0; it < M_; ++it) {
    float bv = -INFINITY; int bi = N_;
    for (int i = tid; i < N_; i += 256) {
      const float v = sS[i];
      if (v > bv || (v == bv && i < bi)) { bv = v; bi = i; }
    }
    red[tid] = bv; redi[tid] = bi; __syncthreads();
    for (int st = 128; st > 0; st >>= 1) {
      if (tid < st) {
        const float v = red[tid + st]; const int j = redi[tid + st];
        if (v > red[tid] || (v == red[tid] && j < redi[tid])) { red[tid] = v; redi[tid] = j; }
      }
      __syncthreads();
    }
    if (tid == 0) { top_idx[b * M_ + it] = redi[0]; sS[redi[0]] = -INFINITY; }
    __syncthreads();
  }
}

// ---------------------------------------------------------------------------
// K3: H0[b,m,:] = (X[b, idx[m], :] @ t2n) * mask   grid 64 = 8 batches x 8 groups
// ---------------------------------------------------------------------------
__global__ __launch_bounds__(256) void k_h0(
    const float* __restrict__ X, const float* __restrict__ t2n,
    const int* __restrict__ top_idx, const int* __restrict__ take_k,
    float* __restrict__ H0)
{
  const int b  = blockIdx.x >> 3;
  const int mg = blockIdx.x & 7;
  const int tid = threadIdx.x;
  const int tk = take_k[b];
  #pragma unroll
  for (int p = 0; p < 2; ++p) {
    const int o = tid + p * 256;
    const int ml = o >> 6, k = o & 63;
    const int m = mg * 8 + ml;
    const int idx = top_idx[b * M_ + m];
    const float* xr = X + ((size_t)b * N_ + idx) * D_;
    float ac0 = 0.f, ac1 = 0.f, ac2 = 0.f, ac3 = 0.f;
    #pragma unroll 4
    for (int d = 0; d < D_; d += 4) {
      const float4 xv = *(const float4*)(xr + d);
      ac0 = fmaf(xv.x, t2n[(d + 0) * 64 + k], ac0);
      ac1 = fmaf(xv.y, t2n[(d + 1) * 64 + k], ac1);
      ac2 = fmaf(xv.z, t2n[(d + 2) * 64 + k], ac2);
      ac3 = fmaf(xv.w, t2n[(d + 3) * 64 + k], ac3);
    }
    const float mk = (m < tk) ? 1.f : 0.f;
    H0[(size_t)b * M_ * 64 + m * 64 + k] = ((ac0 + ac1) + (ac2 + ac3)) * mk;
  }
}

// ---------------------------------------------------------------------------
// K4: cosine adjacency + row-norm + 2-layer GCN -> Hg  (one block per batch)
// ---------------------------------------------------------------------------
__global__ __launch_bounds__(256) void k_graph(
    const float* __restrict__ H0g, const float* __restrict__ g1,
    const float* __restrict__ g2, const int* __restrict__ take_k,
    float* __restrict__ Hgg)
{
  __shared__ float sH0[64][65];
  __shared__ float sA [64][65];
  __shared__ float sT [64][65];
  __shared__ float sU [64][65];   // Hn, then X1
  __shared__ float sR [64];
  const int b = blockIdx.x, tid = threadIdx.x;
  const int tk = take_k[b];
  for (int o = tid; o < 4096; o += 256) sH0[o >> 6][o & 63] = H0g[(size_t)b * 4096 + o];
  __syncthreads();
  if (tid < 64) {
    float s = 0.f;
    #pragma unroll
    for (int k = 0; k < 64; ++k) { const float v = sH0[tid][k]; s = fmaf(v, v, s); }
    sR[tid] = fmaxf(sqrtf(s), 1e-6f);
  }
  __syncthreads();
  for (int o = tid; o < 4096; o += 256) sU[o >> 6][o & 63] = sH0[o >> 6][o & 63] / sR[o >> 6];
  __syncthreads();
  for (int o = tid; o < 4096; o += 256) {
    const int i = o >> 6, j = o & 63;
    float s = 0.f;
    #pragma unroll
    for (int k = 0; k < 64; ++k) s = fmaf(sU[i][k], sU[j][k], s);
    s = fmaxf(s, 0.f);
    const float mi = (i < tk) ? 1.f : 0.f, mj = (j < tk) ? 1.f : 0.f;
    sA[i][j] = s * mi * mj + ((i == j) ? mi : 0.f);
  }
  __syncthreads();
  if (tid < 64) {
    float rs = 0.f;
    #pragma unroll
    for (int j = 0; j < 64; ++j) rs += sA[tid][j];
    sR[tid] = 1.f / fmaxf(rs, 1e-6f);
  }
  __syncthreads();
  for (int o = tid; o < 4096; o += 256) sA[o >> 6][o & 63] *= sR[o >> 6];
  __syncthreads();
  for (int o = tid; o < 4096; o += 256) {               // T = A @ H0
    const int i = o >> 6, k = o & 63;
    float s = 0.f;
    #pragma unroll
    for (int j = 0; j < 64; ++j) s = fmaf(sA[i][j], sH0[j][k], s);
    sT[i][k] = s;
  }
  __syncthreads();
  for (int o = tid; o < 4096; o += 256) {               // X1 = relu(T @ g1)
    const int i = o >> 6, l = o & 63;
    float s = 0.f;
    #pragma unroll
    for (int k = 0; k < 64; ++k) s = fmaf(sT[i][k], g1[k * 64 + l], s);
    sU[i][l] = fmaxf(s, 0.f);
  }
  __syncthreads();
  for (int o = tid; o < 4096; o += 256) {               // T = A @ X1
    const int i = o >> 6, k = o & 63;
    float s = 0.f;
    #pragma unroll
    for (int j = 0; j < 64; ++j) s = fmaf(sA[i][j], sU[j][k], s);
    sT[i][k] = s;
  }
  __syncthreads();
  for (int o = tid; o < 4096; o += 256) {               // Hg = relu(T @ g2)
    const int i = o >> 6, l = o & 63;
    float s = 0.f;
    #pragma unroll
    for (int k = 0; k < 64; ++k) s = fmaf(sT[i][k], g2[k * 64 + l], s);
    Hgg[(size_t)b * 4096 + i * 64 + l] = fmaxf(s, 0.f);
  }
}

// ---------------------------------------------------------------------------
// K5: proj -> logits -> softmax -> inject -> back -> out = X + back
// 64-token tile per block, grid = 8*128 = 1024
// ---------------------------------------------------------------------------
__global__ __launch_bounds__(256, 2) void k_attn(
    const float* __restrict__ X, const float* __restrict__ t2n,
    const float* __restrict__ n2t, const float* __restrict__ Hgg,
    float* __restrict__ out)
{
  __shared__ __align__(16) float sHg [64][68];  // [m][k]
  __shared__ __align__(16) float bufA[64][68];  // X^T staging [k][t] ; logits [m][t]
  __shared__ __align__(16) float bufB[64][68];  // t2n chunk [k][c] ; n2t chunk [k][d]
  __shared__ __align__(16) float bufP[64][68];  // proj^T [c][t] ; inject [t][k]
  const int tid = threadIdx.x;
  const int b  = blockIdx.x >> 7;
  const int t0 = (blockIdx.x & 127) << 6;
  const float* Xb = X + (size_t)b * N_ * D_;
  float* Ob = out + (size_t)b * N_ * D_;
  for (int o = tid; o < 4096; o += 256) sHg[o >> 6][o & 63] = Hgg[(size_t)b * 4096 + o];
  const int tx = tid & 15, ty = tid >> 4;

  // ---- proj GEMM: proj[t][c], t = ty*4+i, c = tx*4+j
  float acc[4][4];
  #pragma unroll
  for (int i = 0; i < 4; ++i)
    #pragma unroll
    for (int j = 0; j < 4; ++j) acc[i][j] = 0.f;

  for (int kk = 0; kk < 8; ++kk) {
    const int k0 = kk * 64;
    __syncthreads();
    {
      const int r = tid >> 4, c4 = tid & 15;
      #pragma unroll
      for (int p = 0; p < 4; ++p) {
        const int rr = r + p * 16;
        float4 w = *(const float4*)(t2n + (size_t)(k0 + rr) * 64 + c4 * 4);
        *(float4*)&bufB[rr][c4 * 4] = w;
        float4 v = *(const float4*)(Xb + (size_t)(t0 + rr) * D_ + k0 + c4 * 4);
        bufA[c4 * 4 + 0][rr] = v.x;
        bufA[c4 * 4 + 1][rr] = v.y;
        bufA[c4 * 4 + 2][rr] = v.z;
        bufA[c4 * 4 + 3][rr] = v.w;
      }
    }
    __syncthreads();
    #pragma unroll 8
    for (int k = 0; k < 64; ++k) {
      const float4 a = *(const float4*)&bufA[k][ty * 4];
      const float4 w = *(const float4*)&bufB[k][tx * 4];
      const float av[4] = {a.x, a.y, a.z, a.w};
      const float wv[4] = {w.x, w.y, w.z, w.w};
      #pragma unroll
      for (int i = 0; i < 4; ++i)
        #pragma unroll
        for (int j = 0; j < 4; ++j) acc[i][j] = fmaf(av[i], wv[j], acc[i][j]);
    }
  }
  __syncthreads();
  #pragma unroll
  for (int i = 0; i < 4; ++i)
    #pragma unroll
    for (int j = 0; j < 4; ++j) bufP[tx * 4 + j][ty * 4 + i] = acc[i][j];  // proj^T
  __syncthreads();

  // ---- logits[m][t] = 0.125 * sum_k proj[t][k] * Hg[m][k]
  for (int o = tid; o < 4096; o += 256) {
    const int m = o >> 6, t = o & 63;
    float s = 0.f;
    #pragma unroll
    for (int k = 0; k < 64; ++k) s = fmaf(bufP[k][t], sHg[m][k], s);
    bufA[m][t] = s * 0.125f;
  }
  __syncthreads();

  // ---- softmax over m (4 threads per token)
  {
    const int t = tid >> 2, q = tid & 3;
    float vals[16];
    float mx = -INFINITY;
    #pragma unroll
    for (int i = 0; i < 16; ++i) { vals[i] = bufA[q * 16 + i][t]; mx = fmaxf(mx, vals[i]); }
    mx = fmaxf(mx, __shfl_xor(mx, 1, 4));
    mx = fmaxf(mx, __shfl_xor(mx, 2, 4));
    float sm = 0.f;
    #pragma unroll
    for (int i = 0; i < 16; ++i) { vals[i] = __expf(vals[i] - mx); sm += vals[i]; }
    sm += __shfl_xor(sm, 1, 4);
    sm += __shfl_xor(sm, 2, 4);
    const float inv = 1.f / sm;
    #pragma unroll
    for (int i = 0; i < 16; ++i) bufA[q * 16 + i][t] = vals[i] * inv;
  }
  __syncthreads();

  // ---- inject[t][k] = sum_m attn[m][t] * Hg[m][k]   (overwrite bufP)
  for (int o = tid; o < 4096; o += 256) {
    const int t = o >> 6, k = o & 63;
    float s = 0.f;
    #pragma unroll
    for (int m = 0; m < 64; ++m) s = fmaf(bufA[m][t], sHg[m][k], s);
    bufP[t][k] = s;
  }
  __syncthreads();

  // ---- back GEMM per 64-wide d-chunk + residual add
  for (int dd = 0; dd < 8; ++dd) {
    const int d0 = dd * 64;
    __syncthreads();
    {
      const int r = tid >> 4, c4 = tid & 15;
      #pragma unroll
      for (int p = 0; p < 4; ++p) {
        const int rr = r + p * 16;
        float4 w = *(const float4*)(n2t + (size_t)rr * D_ + d0 + c4 * 4);
        *(float4*)&bufB[rr][c4 * 4] = w;
      }
    }
    __syncthreads();
    float o2[4][4];
    #pragma unroll
    for (int i = 0; i < 4; ++i)
      #pragma unroll
      for (int j = 0; j < 4; ++j) o2[i][j] = 0.f;
    #pragma unroll 8
    for (int k = 0; k < 64; ++k) {
      const float4 w = *(const float4*)&bufB[k][tx * 4];
      const float wv[4] = {w.x, w.y, w.z, w.w};
      float av[4];
      #pragma unroll
      for (int i = 0; i < 4; ++i) av[i] = bufP[ty * 4 + i][k];
      #pragma unroll
      for (int i = 0; i < 4; ++i)
        #pragma unroll
        for (int j = 0; j < 4; ++j) o2[i][j] = fmaf(av[i], wv[j], o2[i][j]);
    }
    #pragma unroll
    for (int i = 0; i < 4; ++i) {
      const size_t base = (size_t)(t0 + ty * 4 + i) * D_ + d0 + tx * 4;
      const float4 xv = *(const float4*)(Xb + base);
      float4 r4;
      r4.x = xv.x + o2[i][0]; r4.y = xv.y + o2[i][1];
      r4.z = xv.z + o2[i][2]; r4.w = xv.w + o2[i][3];
      *(float4*)(Ob + base) = r4;
    }
  }
}

// ---------------------------------------------------------------------------
extern "C" void kernel_launch(void* const* d_in, const int* in_sizes, int n_in,
                              void* d_out, int out_size, void* d_ws, size_t ws_size,
                              hipStream_t stream)
{
  (void)in_sizes; (void)n_in; (void)out_size; (void)ws_size;
  const float* X   = (const float*)d_in[0];
  const float* W1  = (const float*)d_in[1];
  const float* b1  = (const float*)d_in[2];
  const float* w2  = (const float*)d_in[3];
  const float* b2  = (const float*)d_in[4];
  const float* t2n = (const float*)d_in[5];
  const float* n2t = (const float*)d_in[6];
  const float* g1  = (const float*)d_in[7];
  const float* g2  = (const float*)d_in[8];
  float* out = (float*)d_out;

  char* ws = (char*)d_ws;
  float* scores = (float*)(ws);                         // 65536 floats
  float* H0     = (float*)(ws + 262144);                // 32768 floats
  float* Hg     = (float*)(ws + 262144 + 131072);       // 32768 floats
  int* top_idx  = (int*)(ws + 262144 + 262144);         // 512 ints
  int* take_k   = (int*)(ws + 262144 + 262144 + 2048);  // 8 ints

  k_scores<<<512, 256, 0, stream>>>(X, W1, b1, w2, b2, scores);
  k_select<<<B_, 256, 0, stream>>>(scores, top_idx, take_k);
  k_h0<<<64, 256, 0, stream>>>(X, t2n, top_idx, take_k, H0);
  k_graph<<<B_, 256, 0, stream>>>(H0, g1, g2, take_k, Hg);
  k_attn<<<1024, 256, 0, stream>>>(X, t2n, n2t, Hg, out);
}

// Round 2
// 273.627 us; speedup vs baseline: 2.2485x; 2.2485x over previous
//
#include <hip/hip_runtime.h>
#include <hip/hip_bf16.h>

#define B_ 8
#define N_ 8192
#define D_ 512
#define M_ 64

typedef unsigned short u16;
typedef unsigned int u32;
typedef __attribute__((ext_vector_type(8))) short bf16x8;
typedef __attribute__((ext_vector_type(4))) float f32x4;

__device__ __forceinline__ u16 f2bf(float f) {
  u32 u = __float_as_uint(f);
  u += 0x7FFFu + ((u >> 16) & 1u);
  return (u16)(u >> 16);
}
__device__ __forceinline__ float bf2f(u16 h) {
  return __uint_as_float(((u32)h) << 16);
}

// B-fragment index for matrix Mx[kd][c] with N cols: slot mapping shared by A.
__device__ __forceinline__ int bfrag_idx(int kd, int c, int ncols16) {
  int sub = (kd >> 5) * ncols16 + (c >> 4);
  int lane = (c & 15) + 16 * ((kd & 15) >> 2);
  int e = (kd & 3) + 4 * ((kd >> 4) & 1);
  return sub * 512 + lane * 8 + e;
}

// ---------------------------------------------------------------------------
// k_prep: convert t2n, n2t, W1(hi/lo split) into bf16 B-fragment layout
// ---------------------------------------------------------------------------
__global__ __launch_bounds__(256) void k_prep(
    const float* __restrict__ t2n, const float* __restrict__ n2t,
    const float* __restrict__ W1, u16* __restrict__ t2nf, u16* __restrict__ n2tf,
    u16* __restrict__ W1h, u16* __restrict__ W1l)
{
  const int gid = blockIdx.x * 256 + threadIdx.x;
  const int stride = gridDim.x * 256;
  for (int s = gid; s < 512 * 64; s += stride) {
    const int k = s >> 6, c = s & 63;
    const int idx = bfrag_idx(k, c, 4);
    t2nf[idx] = f2bf(t2n[s]);
    const float w = W1[s];
    const u16 wh = f2bf(w);
    W1h[idx] = wh;
    W1l[idx] = f2bf(w - bf2f(wh));
  }
  for (int s = gid; s < 64 * 512; s += stride) {
    const int k = s >> 9, c = s & 511;
    n2tf[bfrag_idx(k, c, 32)] = f2bf(n2t[s]);
  }
}

// ---------------------------------------------------------------------------
// k_scores: scores = relu(X@W1+b1)@w2+b2 via split-bf16 MFMA (fp32-accurate)
// 64 tokens/block, grid 1024
// ---------------------------------------------------------------------------
__global__ __launch_bounds__(256) void k_scores(
    const float* __restrict__ X, const u16* __restrict__ W1h,
    const u16* __restrict__ W1l, const float* __restrict__ b1,
    const float* __restrict__ w2, const float* __restrict__ b2,
    float* __restrict__ scores)
{
  __shared__ __align__(16) u16 sAh[4096];
  __shared__ __align__(16) u16 sAl[4096];
  const int tid = threadIdx.x;
  const int t0 = blockIdx.x * 64;
  const int wv = tid >> 6, ln = tid & 63;

  f32x4 acc[4];
  #pragma unroll
  for (int cb = 0; cb < 4; ++cb) acc[cb] = (f32x4){0.f, 0.f, 0.f, 0.f};

  for (int ch = 0; ch < 8; ++ch) {
    __syncthreads();
    #pragma unroll
    for (int p = 0; p < 4; ++p) {
      const int i = tid + p * 256;
      const int row = i >> 4, k4 = i & 15;
      const float4 v = *(const float4*)(X + (size_t)(t0 + row) * D_ + ch * 64 + k4 * 4);
      const int idx = ((row >> 4) * 2 + (k4 >> 3)) * 512 +
                      ((row & 15) + 16 * (k4 & 3)) * 8 + 4 * ((k4 >> 2) & 1);
      const u16 h0 = f2bf(v.x), h1 = f2bf(v.y), h2 = f2bf(v.z), h3 = f2bf(v.w);
      const u16 l0 = f2bf(v.x - bf2f(h0)), l1 = f2bf(v.y - bf2f(h1));
      const u16 l2 = f2bf(v.z - bf2f(h2)), l3 = f2bf(v.w - bf2f(h3));
      *(uint2*)&sAh[idx] = make_uint2((u32)h0 | ((u32)h1 << 16), (u32)h2 | ((u32)h3 << 16));
      *(uint2*)&sAl[idx] = make_uint2((u32)l0 | ((u32)l1 << 16), (u32)l2 | ((u32)l3 << 16));
    }
    __syncthreads();
    #pragma unroll
    for (int kb = 0; kb < 2; ++kb) {
      const bf16x8 ah = *(const bf16x8*)&sAh[(wv * 2 + kb) * 512 + ln * 8];
      const bf16x8 al = *(const bf16x8*)&sAl[(wv * 2 + kb) * 512 + ln * 8];
      #pragma unroll
      for (int cb = 0; cb < 4; ++cb) {
        const bf16x8 bh = *(const bf16x8*)&W1h[((ch * 2 + kb) * 4 + cb) * 512 + ln * 8];
        const bf16x8 bl = *(const bf16x8*)&W1l[((ch * 2 + kb) * 4 + cb) * 512 + ln * 8];
        acc[cb] = __builtin_amdgcn_mfma_f32_16x16x32_bf16(ah, bh, acc[cb], 0, 0, 0);
        acc[cb] = __builtin_amdgcn_mfma_f32_16x16x32_bf16(ah, bl, acc[cb], 0, 0, 0);
        acc[cb] = __builtin_amdgcn_mfma_f32_16x16x32_bf16(al, bh, acc[cb], 0, 0, 0);
      }
    }
  }
  float b1v[4], w2v[4];
  #pragma unroll
  for (int cb = 0; cb < 4; ++cb) {
    const int col = cb * 16 + (ln & 15);
    b1v[cb] = b1[col]; w2v[cb] = w2[col];
  }
  const float b2v = b2[0];
  #pragma unroll
  for (int r = 0; r < 4; ++r) {
    float p = 0.f;
    #pragma unroll
    for (int cb = 0; cb < 4; ++cb) {
      const float h = fmaxf(acc[cb][r] + b1v[cb], 0.f);
      p = fmaf(h, w2v[cb], p);
    }
    p += __shfl_xor(p, 1); p += __shfl_xor(p, 2);
    p += __shfl_xor(p, 4); p += __shfl_xor(p, 8);
    if ((ln & 15) == 0) scores[t0 + wv * 16 + 4 * (ln >> 4) + r] = p + b2v;
  }
}

// ---------------------------------------------------------------------------
// k_select: stats + exact top-64 via 4-pass radix select on key bits
// ---------------------------------------------------------------------------
__global__ __launch_bounds__(256) void k_select(
    const float* __restrict__ scores, int* __restrict__ top_idx,
    int* __restrict__ take_k)
{
  __shared__ float sS[N_];
  __shared__ u32 hist[256];
  __shared__ float redf[256];
  __shared__ u32 sPrefix, sRank, sCntA, sCntT;
  __shared__ int candIdx[64];
  __shared__ float candVal[64];
  __shared__ int tieIdx[128];
  const int b = blockIdx.x, tid = threadIdx.x;
  const float* s = scores + (size_t)b * N_;
  float sum = 0.f, sq = 0.f;
  for (int i = tid; i < N_; i += 256) {
    const float v = s[i]; sS[i] = v; sum += v; sq = fmaf(v, v, sq);
  }
  redf[tid] = sum; __syncthreads();
  for (int st = 128; st > 0; st >>= 1) { if (tid < st) redf[tid] += redf[tid + st]; __syncthreads(); }
  const float tot = redf[0]; __syncthreads();
  redf[tid] = sq; __syncthreads();
  for (int st = 128; st > 0; st >>= 1) { if (tid < st) redf[tid] += redf[tid + st]; __syncthreads(); }
  const float mean = tot / (float)N_;
  const float var = redf[0] / (float)N_ - mean * mean;
  const float thr = mean + 0.5f * sqrtf(fmaxf(var, 0.f));
  __syncthreads();
  int c = 0;
  for (int i = tid; i < N_; i += 256) c += (sS[i] > thr) ? 1 : 0;
  hist[tid] = (u32)c; __syncthreads();
  for (int st = 128; st > 0; st >>= 1) { if (tid < st) hist[tid] += hist[tid + st]; __syncthreads(); }
  if (tid == 0) {
    const int cnt = (int)hist[0];
    take_k[b] = (cnt == 0) ? M_ : (cnt < M_ ? cnt : M_);
  }
  __syncthreads();
  u32 prefix = 0, rank = 64, pmask = 0;
  for (int pass = 0; pass < 4; ++pass) {
    const int shift = 24 - 8 * pass;
    hist[tid] = 0;
    __syncthreads();
    for (int i = tid; i < N_; i += 256) {
      const u32 u = __float_as_uint(sS[i]);
      const u32 key = u ^ ((u32)((int)u >> 31) | 0x80000000u);
      if ((key & pmask) == prefix) atomicAdd(&hist[(key >> shift) & 255u], 1u);
    }
    __syncthreads();
    if (tid == 0) {
      u32 cum = 0;
      for (int cc = 255; cc >= 0; --cc) {
        cum += hist[cc];
        if (cum >= rank) {
          sPrefix = prefix | ((u32)cc << shift);
          sRank = rank - (cum - hist[cc]);
          break;
        }
      }
    }
    __syncthreads();
    prefix = sPrefix; rank = sRank;
    pmask |= 0xFFu << shift;
    __syncthreads();
  }
  if (tid == 0) { sCntA = 0; sCntT = 0; }
  __syncthreads();
  const u32 pivot = prefix;
  for (int i = tid; i < N_; i += 256) {
    const u32 u = __float_as_uint(sS[i]);
    const u32 key = u ^ ((u32)((int)u >> 31) | 0x80000000u);
    if (key > pivot) {
      const u32 p = atomicAdd(&sCntA, 1u);
      candIdx[p] = i; candVal[p] = sS[i];
    } else if (key == pivot) {
      const u32 p = atomicAdd(&sCntT, 1u);
      if (p < 128) tieIdx[p] = i;
    }
  }
  __syncthreads();
  if (tid == 0) {
    const int nA = (int)sCntA;
    const int need = 64 - nA;
    int nT = (int)sCntT; if (nT > 128) nT = 128;
    for (int j = 0; j < need; ++j) {
      int bi = 1 << 30, bp = -1;
      for (int q = 0; q < nT; ++q) {
        const int v = tieIdx[q];
        if (v >= 0 && v < bi) { bi = v; bp = q; }
      }
      candIdx[nA + j] = bi; candVal[nA + j] = sS[bi]; tieIdx[bp] = -1;
    }
  }
  __syncthreads();
  if (tid < 64) {
    const float v = candVal[tid]; const int ii = candIdx[tid];
    int rk = 0;
    for (int j = 0; j < 64; ++j) {
      const float vj = candVal[j]; const int ij = candIdx[j];
      rk += (vj > v || (vj == v && ij < ii)) ? 1 : 0;
    }
    top_idx[b * M_ + rk] = ii;
  }
}

// ---------------------------------------------------------------------------
// k_h0 (fp32, exact): H0[b,m,:] = (X[b, idx[m], :] @ t2n) * mask
// ---------------------------------------------------------------------------
__global__ __launch_bounds__(256) void k_h0(
    const float* __restrict__ X, const float* __restrict__ t2n,
    const int* __restrict__ top_idx, const int* __restrict__ take_k,
    float* __restrict__ H0)
{
  const int b = blockIdx.x >> 3;
  const int mg = blockIdx.x & 7;
  const int tid = threadIdx.x;
  const int tk = take_k[b];
  #pragma unroll
  for (int p = 0; p < 2; ++p) {
    const int o = tid + p * 256;
    const int ml = o >> 6, k = o & 63;
    const int m = mg * 8 + ml;
    const int idx = top_idx[b * M_ + m];
    const float* xr = X + ((size_t)b * N_ + idx) * D_;
    float ac0 = 0.f, ac1 = 0.f, ac2 = 0.f, ac3 = 0.f;
    #pragma unroll 4
    for (int d = 0; d < D_; d += 4) {
      const float4 xv = *(const float4*)(xr + d);
      ac0 = fmaf(xv.x, t2n[(d + 0) * 64 + k], ac0);
      ac1 = fmaf(xv.y, t2n[(d + 1) * 64 + k], ac1);
      ac2 = fmaf(xv.z, t2n[(d + 2) * 64 + k], ac2);
      ac3 = fmaf(xv.w, t2n[(d + 3) * 64 + k], ac3);
    }
    const float mk = (m < tk) ? 1.f : 0.f;
    H0[(size_t)b * M_ * 64 + m * 64 + k] = ((ac0 + ac1) + (ac2 + ac3)) * mk;
  }
}

// ---------------------------------------------------------------------------
// k_graph: adjacency + 2-layer GCN; emits Hg as bf16 B-fragments for
// logits (HgT: kd=featk, c=m) and inject (Hg: kd=m, c=featk)
// ---------------------------------------------------------------------------
__global__ __launch_bounds__(256) void k_graph(
    const float* __restrict__ H0g, const float* __restrict__ g1,
    const float* __restrict__ g2, const int* __restrict__ take_k,
    u16* __restrict__ HgTf, u16* __restrict__ Hgf)
{
  __shared__ float sH0[64][65];
  __shared__ float sA[64][65];
  __shared__ float sT[64][65];
  __shared__ float sU[64][65];
  __shared__ float sR[64];
  const int b = blockIdx.x, tid = threadIdx.x;
  const int tk = take_k[b];
  for (int o = tid; o < 4096; o += 256) sH0[o >> 6][o & 63] = H0g[(size_t)b * 4096 + o];
  __syncthreads();
  if (tid < 64) {
    float s = 0.f;
    #pragma unroll
    for (int k = 0; k < 64; ++k) { const float v = sH0[tid][k]; s = fmaf(v, v, s); }
    sR[tid] = fmaxf(sqrtf(s), 1e-6f);
  }
  __syncthreads();
  for (int o = tid; o < 4096; o += 256) sU[o >> 6][o & 63] = sH0[o >> 6][o & 63] / sR[o >> 6];
  __syncthreads();
  for (int o = tid; o < 4096; o += 256) {
    const int i = o >> 6, j = o & 63;
    float s = 0.f;
    #pragma unroll
    for (int k = 0; k < 64; ++k) s = fmaf(sU[i][k], sU[j][k], s);
    s = fmaxf(s, 0.f);
    const float mi = (i < tk) ? 1.f : 0.f, mj = (j < tk) ? 1.f : 0.f;
    sA[i][j] = s * mi * mj + ((i == j) ? mi : 0.f);
  }
  __syncthreads();
  if (tid < 64) {
    float rs = 0.f;
    #pragma unroll
    for (int j = 0; j < 64; ++j) rs += sA[tid][j];
    sR[tid] = 1.f / fmaxf(rs, 1e-6f);
  }
  __syncthreads();
  for (int o = tid; o < 4096; o += 256) sA[o >> 6][o & 63] *= sR[o >> 6];
  __syncthreads();
  for (int o = tid; o < 4096; o += 256) {
    const int i = o >> 6, k = o & 63;
    float s = 0.f;
    #pragma unroll
    for (int j = 0; j < 64; ++j) s = fmaf(sA[i][j], sH0[j][k], s);
    sT[i][k] = s;
  }
  __syncthreads();
  for (int o = tid; o < 4096; o += 256) {
    const int i = o >> 6, l = o & 63;
    float s = 0.f;
    #pragma unroll
    for (int k = 0; k < 64; ++k) s = fmaf(sT[i][k], g1[k * 64 + l], s);
    sU[i][l] = fmaxf(s, 0.f);
  }
  __syncthreads();
  for (int o = tid; o < 4096; o += 256) {
    const int i = o >> 6, k = o & 63;
    float s = 0.f;
    #pragma unroll
    for (int j = 0; j < 64; ++j) s = fmaf(sA[i][j], sU[j][k], s);
    sT[i][k] = s;
  }
  __syncthreads();
  for (int o = tid; o < 4096; o += 256) {
    const int i = o >> 6, l = o & 63;  // i = node m, l = feature k
    float s = 0.f;
    #pragma unroll
    for (int k = 0; k < 64; ++k) s = fmaf(sT[i][k], g2[k * 64 + l], s);
    const u16 hb = f2bf(fmaxf(s, 0.f));
    HgTf[(size_t)b * 4096 + bfrag_idx(l, i, 4)] = hb;  // B for logits: kd=featk, col=m
    Hgf [(size_t)b * 4096 + bfrag_idx(i, l, 4)] = hb;  // B for inject: kd=m, col=featk
  }
}

// ---------------------------------------------------------------------------
// k_attn: proj->logits->softmax->inject->back->residual, all GEMMs via MFMA
// 64 tokens/block, grid 1024, softmax fully in registers on D-fragments
// ---------------------------------------------------------------------------
__global__ __launch_bounds__(256) void k_attn(
    const float* __restrict__ X, const u16* __restrict__ t2nf,
    const u16* __restrict__ n2tf, const u16* __restrict__ HgTf,
    const u16* __restrict__ Hgf, float* __restrict__ out)
{
  __shared__ __align__(16) u16 sAf[4096];
  const int tid = threadIdx.x;
  const int b = blockIdx.x >> 7;
  const int t0 = (blockIdx.x & 127) << 6;
  const float* Xb = X + (size_t)b * N_ * D_;
  float* Ob = out + (size_t)b * N_ * D_;
  const int wv = tid >> 6, ln = tid & 63;
  const int lq = ln >> 4, lr = ln & 15;

  // ---- P1: proj = X_tile @ t2n (bf16 MFMA over K=512)
  f32x4 acc[4];
  #pragma unroll
  for (int cb = 0; cb < 4; ++cb) acc[cb] = (f32x4){0.f, 0.f, 0.f, 0.f};
  for (int ch = 0; ch < 8; ++ch) {
    __syncthreads();
    #pragma unroll
    for (int p = 0; p < 4; ++p) {
      const int i = tid + p * 256;
      const int row = i >> 4, k4 = i & 15;
      const float4 v = *(const float4*)(Xb + (size_t)(t0 + row) * D_ + ch * 64 + k4 * 4);
      const int idx = ((row >> 4) * 2 + (k4 >> 3)) * 512 +
                      ((row & 15) + 16 * (k4 & 3)) * 8 + 4 * ((k4 >> 2) & 1);
      *(uint2*)&sAf[idx] = make_uint2((u32)f2bf(v.x) | ((u32)f2bf(v.y) << 16),
                                      (u32)f2bf(v.z) | ((u32)f2bf(v.w) << 16));
    }
    __syncthreads();
    #pragma unroll
    for (int kb = 0; kb < 2; ++kb) {
      const bf16x8 a = *(const bf16x8*)&sAf[(wv * 2 + kb) * 512 + ln * 8];
      #pragma unroll
      for (int cb = 0; cb < 4; ++cb) {
        const bf16x8 bb = *(const bf16x8*)&t2nf[((ch * 2 + kb) * 4 + cb) * 512 + ln * 8];
        acc[cb] = __builtin_amdgcn_mfma_f32_16x16x32_bf16(a, bb, acc[cb], 0, 0, 0);
      }
    }
  }
  __syncthreads();
  // write proj as bf16 A-fragments (wave-local region: subs wv*2, wv*2+1)
  #pragma unroll
  for (int cb = 0; cb < 4; ++cb)
    #pragma unroll
    for (int r = 0; r < 4; ++r) {
      const int col = 16 * cb + lr;
      const int idx = (wv * 2 + (col >> 5)) * 512 +
                      (4 * lq + r + 16 * ((col & 15) >> 2)) * 8 +
                      ((col & 3) + 4 * ((col >> 4) & 1));
      sAf[idx] = f2bf(acc[cb][r]);
    }
  __syncthreads();

  // ---- P2: logits = proj @ Hg^T  (K=64)
  f32x4 accL[4];
  #pragma unroll
  for (int cb = 0; cb < 4; ++cb) accL[cb] = (f32x4){0.f, 0.f, 0.f, 0.f};
  #pragma unroll
  for (int kb = 0; kb < 2; ++kb) {
    const bf16x8 a = *(const bf16x8*)&sAf[(wv * 2 + kb) * 512 + ln * 8];
    #pragma unroll
    for (int cb = 0; cb < 4; ++cb) {
      const bf16x8 bb = *(const bf16x8*)&HgTf[(size_t)b * 4096 + (kb * 4 + cb) * 512 + ln * 8];
      accL[cb] = __builtin_amdgcn_mfma_f32_16x16x32_bf16(a, bb, accL[cb], 0, 0, 0);
    }
  }

  // ---- P3: softmax over m in registers (row r owned by 16-lane group)
  float attnv[4][4];
  #pragma unroll
  for (int r = 0; r < 4; ++r) {
    const float v0 = accL[0][r], v1 = accL[1][r], v2 = accL[2][r], v3 = accL[3][r];
    float mx = fmaxf(fmaxf(v0, v1), fmaxf(v2, v3));
    mx = fmaxf(mx, __shfl_xor(mx, 1)); mx = fmaxf(mx, __shfl_xor(mx, 2));
    mx = fmaxf(mx, __shfl_xor(mx, 4)); mx = fmaxf(mx, __shfl_xor(mx, 8));
    const float e0 = __expf((v0 - mx) * 0.125f), e1 = __expf((v1 - mx) * 0.125f);
    const float e2 = __expf((v2 - mx) * 0.125f), e3 = __expf((v3 - mx) * 0.125f);
    float sm = (e0 + e1) + (e2 + e3);
    sm += __shfl_xor(sm, 1); sm += __shfl_xor(sm, 2);
    sm += __shfl_xor(sm, 4); sm += __shfl_xor(sm, 8);
    const float inv = 1.f / sm;
    attnv[0][r] = e0 * inv; attnv[1][r] = e1 * inv;
    attnv[2][r] = e2 * inv; attnv[3][r] = e3 * inv;
  }
  __syncthreads();
  // write attn as bf16 A-fragments
  #pragma unroll
  for (int cb = 0; cb < 4; ++cb)
    #pragma unroll
    for (int r = 0; r < 4; ++r) {
      const int col = 16 * cb + lr;
      const int idx = (wv * 2 + (col >> 5)) * 512 +
                      (4 * lq + r + 16 * ((col & 15) >> 2)) * 8 +
                      ((col & 3) + 4 * ((col >> 4) & 1));
      sAf[idx] = f2bf(attnv[cb][r]);
    }

  // ---- P5: inject = attn @ Hg (K=64)
  f32x4 accI[4];
  #pragma unroll
  for (int cb = 0; cb < 4; ++cb) accI[cb] = (f32x4){0.f, 0.f, 0.f, 0.f};
  #pragma unroll
  for (int kb = 0; kb < 2; ++kb) {
    const bf16x8 a = *(const bf16x8*)&sAf[(wv * 2 + kb) * 512 + ln * 8];
    #pragma unroll
    for (int cb = 0; cb < 4; ++cb) {
      const bf16x8 bb = *(const bf16x8*)&Hgf[(size_t)b * 4096 + (kb * 4 + cb) * 512 + ln * 8];
      accI[cb] = __builtin_amdgcn_mfma_f32_16x16x32_bf16(a, bb, accI[cb], 0, 0, 0);
    }
  }
  // write inject as bf16 A-fragments
  #pragma unroll
  for (int cb = 0; cb < 4; ++cb)
    #pragma unroll
    for (int r = 0; r < 4; ++r) {
      const int col = 16 * cb + lr;
      const int idx = (wv * 2 + (col >> 5)) * 512 +
                      (4 * lq + r + 16 * ((col & 15) >> 2)) * 8 +
                      ((col & 3) + 4 * ((col >> 4) & 1));
      sAf[idx] = f2bf(accI[cb][r]);
    }

  // ---- P7: back = inject @ n2t (K=64, N=512 in 4 chunks) + residual
  for (int chk = 0; chk < 4; ++chk) {
    f32x4 accB[8];
    #pragma unroll
    for (int c8 = 0; c8 < 8; ++c8) accB[c8] = (f32x4){0.f, 0.f, 0.f, 0.f};
    #pragma unroll
    for (int kb = 0; kb < 2; ++kb) {
      const bf16x8 a = *(const bf16x8*)&sAf[(wv * 2 + kb) * 512 + ln * 8];
      #pragma unroll
      for (int c8 = 0; c8 < 8; ++c8) {
        const int gcb = chk * 8 + c8;
        const bf16x8 bb = *(const bf16x8*)&n2tf[(kb * 32 + gcb) * 512 + ln * 8];
        accB[c8] = __builtin_amdgcn_mfma_f32_16x16x32_bf16(a, bb, accB[c8], 0, 0, 0);
      }
    }
    #pragma unroll
    for (int c8 = 0; c8 < 8; ++c8)
      #pragma unroll
      for (int r = 0; r < 4; ++r) {
        const int row = t0 + 16 * wv + 4 * lq + r;
        const int col = chk * 128 + 16 * c8 + lr;
        const size_t off = (size_t)row * D_ + col;
        Ob[off] = Xb[off] + accB[c8][r];
      }
  }
}

// ---------------------------------------------------------------------------
extern "C" void kernel_launch(void* const* d_in, const int* in_sizes, int n_in,
                              void* d_out, int out_size, void* d_ws, size_t ws_size,
                              hipStream_t stream)
{
  (void)in_sizes; (void)n_in; (void)out_size; (void)ws_size;
  const float* X   = (const float*)d_in[0];
  const float* W1  = (const float*)d_in[1];
  const float* b1  = (const float*)d_in[2];
  const float* w2  = (const float*)d_in[3];
  const float* b2  = (const float*)d_in[4];
  const float* t2n = (const float*)d_in[5];
  const float* n2t = (const float*)d_in[6];
  const float* g1  = (const float*)d_in[7];
  const float* g2  = (const float*)d_in[8];
  float* out = (float*)d_out;

  char* ws = (char*)d_ws;
  float* scores = (float*)(ws);                 // 256 KB
  float* H0     = (float*)(ws + 262144);        // 128 KB
  u16* t2nf     = (u16*)(ws + 393216);          // 64 KB
  u16* n2tf     = (u16*)(ws + 458752);          // 64 KB
  u16* W1h      = (u16*)(ws + 524288);          // 64 KB
  u16* W1l      = (u16*)(ws + 589824);          // 64 KB
  u16* HgTf     = (u16*)(ws + 655360);          // 64 KB
  u16* Hgf      = (u16*)(ws + 720896);          // 64 KB
  int* top_idx  = (int*)(ws + 786432);          // 2 KB
  int* take_k   = (int*)(ws + 788480);          // 32 B

  k_prep<<<64, 256, 0, stream>>>(t2n, n2t, W1, t2nf, n2tf, W1h, W1l);
  k_scores<<<1024, 256, 0, stream>>>(X, W1h, W1l, b1, w2, b2, scores);
  k_select<<<B_, 256, 0, stream>>>(scores, top_idx, take_k);
  k_h0<<<64, 256, 0, stream>>>(X, t2n, top_idx, take_k, H0);
  k_graph<<<B_, 256, 0, stream>>>(H0, g1, g2, take_k, HgTf, Hgf);
  k_attn<<<1024, 256, 0, stream>>>(X, t2nf, n2tf, HgTf, Hgf, out);
}

// Round 3
// 202.003 us; speedup vs baseline: 3.0458x; 1.3546x over previous
//
#include <hip/hip_runtime.h>
#include <hip/hip_bf16.h>

#define B_ 8
#define N_ 8192
#define D_ 512
#define M_ 64

typedef unsigned short u16;
typedef unsigned int u32;
typedef __attribute__((ext_vector_type(8))) short bf16x8;
typedef __attribute__((ext_vector_type(4))) float f32x4;

__device__ __forceinline__ u16 f2bf(float f) {
  u32 u = __float_as_uint(f);
  u += 0x7FFFu + ((u >> 16) & 1u);
  return (u16)(u >> 16);
}
__device__ __forceinline__ float bf2f(u16 h) {
  return __uint_as_float(((u32)h) << 16);
}

// B-fragment index for matrix Mx[kd][c] with N cols: slot mapping shared by A.
__device__ __forceinline__ int bfrag_idx(int kd, int c, int ncols16) {
  int sub = (kd >> 5) * ncols16 + (c >> 4);
  int lane = (c & 15) + 16 * ((kd & 15) >> 2);
  int e = (kd & 3) + 4 * ((kd >> 4) & 1);
  return sub * 512 + lane * 8 + e;
}

// fragment k-slot for (lane, elem) within a 32-k block
__device__ __forceinline__ int kslot(int ln, int e) {
  return (e & 3) + 4 * (ln >> 4) + 16 * (e >> 2);
}

// ---------------------------------------------------------------------------
// k_prep: weights -> bf16 fragment layouts (t2n, n2t, W1 hi/lo, g1, g2)
// ---------------------------------------------------------------------------
__global__ __launch_bounds__(256) void k_prep(
    const float* __restrict__ t2n, const float* __restrict__ n2t,
    const float* __restrict__ W1, const float* __restrict__ g1,
    const float* __restrict__ g2,
    u16* __restrict__ t2nf, u16* __restrict__ n2tf,
    u16* __restrict__ W1h, u16* __restrict__ W1l,
    u16* __restrict__ g1f, u16* __restrict__ g2f)
{
  const int gid = blockIdx.x * 256 + threadIdx.x;
  const int stride = gridDim.x * 256;
  for (int s = gid; s < 512 * 64; s += stride) {
    const int k = s >> 6, c = s & 63;
    const int idx = bfrag_idx(k, c, 4);
    t2nf[idx] = f2bf(t2n[s]);
    const float w = W1[s];
    const u16 wh = f2bf(w);
    W1h[idx] = wh;
    W1l[idx] = f2bf(w - bf2f(wh));
  }
  for (int s = gid; s < 64 * 512; s += stride) {
    const int k = s >> 9, c = s & 511;
    n2tf[bfrag_idx(k, c, 32)] = f2bf(n2t[s]);
  }
  for (int s = gid; s < 4096; s += stride) {
    const int k = s >> 6, c = s & 63;
    g1f[bfrag_idx(k, c, 4)] = f2bf(g1[s]);
    g2f[bfrag_idx(k, c, 4)] = f2bf(g2[s]);
  }
}

// ---------------------------------------------------------------------------
// k_scores: scores = relu(X@W1+b1)@w2+b2 via split-bf16 MFMA (fp32-accurate)
// ---------------------------------------------------------------------------
__global__ __launch_bounds__(256) void k_scores(
    const float* __restrict__ X, const u16* __restrict__ W1h,
    const u16* __restrict__ W1l, const float* __restrict__ b1,
    const float* __restrict__ w2, const float* __restrict__ b2,
    float* __restrict__ scores)
{
  __shared__ __align__(16) u16 sAh[4096];
  __shared__ __align__(16) u16 sAl[4096];
  const int tid = threadIdx.x;
  const int t0 = blockIdx.x * 64;
  const int wv = tid >> 6, ln = tid & 63;

  f32x4 acc[4];
  #pragma unroll
  for (int cb = 0; cb < 4; ++cb) acc[cb] = (f32x4){0.f, 0.f, 0.f, 0.f};

  for (int ch = 0; ch < 8; ++ch) {
    __syncthreads();
    #pragma unroll
    for (int p = 0; p < 4; ++p) {
      const int i = tid + p * 256;
      const int row = i >> 4, k4 = i & 15;
      const float4 v = *(const float4*)(X + (size_t)(t0 + row) * D_ + ch * 64 + k4 * 4);
      const int idx = ((row >> 4) * 2 + (k4 >> 3)) * 512 +
                      ((row & 15) + 16 * (k4 & 3)) * 8 + 4 * ((k4 >> 2) & 1);
      const u16 h0 = f2bf(v.x), h1 = f2bf(v.y), h2 = f2bf(v.z), h3 = f2bf(v.w);
      const u16 l0 = f2bf(v.x - bf2f(h0)), l1 = f2bf(v.y - bf2f(h1));
      const u16 l2 = f2bf(v.z - bf2f(h2)), l3 = f2bf(v.w - bf2f(h3));
      *(uint2*)&sAh[idx] = make_uint2((u32)h0 | ((u32)h1 << 16), (u32)h2 | ((u32)h3 << 16));
      *(uint2*)&sAl[idx] = make_uint2((u32)l0 | ((u32)l1 << 16), (u32)l2 | ((u32)l3 << 16));
    }
    __syncthreads();
    #pragma unroll
    for (int kb = 0; kb < 2; ++kb) {
      const bf16x8 ah = *(const bf16x8*)&sAh[(wv * 2 + kb) * 512 + ln * 8];
      const bf16x8 al = *(const bf16x8*)&sAl[(wv * 2 + kb) * 512 + ln * 8];
      #pragma unroll
      for (int cb = 0; cb < 4; ++cb) {
        const bf16x8 bh = *(const bf16x8*)&W1h[((ch * 2 + kb) * 4 + cb) * 512 + ln * 8];
        const bf16x8 bl = *(const bf16x8*)&W1l[((ch * 2 + kb) * 4 + cb) * 512 + ln * 8];
        acc[cb] = __builtin_amdgcn_mfma_f32_16x16x32_bf16(ah, bh, acc[cb], 0, 0, 0);
        acc[cb] = __builtin_amdgcn_mfma_f32_16x16x32_bf16(ah, bl, acc[cb], 0, 0, 0);
        acc[cb] = __builtin_amdgcn_mfma_f32_16x16x32_bf16(al, bh, acc[cb], 0, 0, 0);
      }
    }
  }
  float b1v[4], w2v[4];
  #pragma unroll
  for (int cb = 0; cb < 4; ++cb) {
    const int col = cb * 16 + (ln & 15);
    b1v[cb] = b1[col]; w2v[cb] = w2[col];
  }
  const float b2v = b2[0];
  #pragma unroll
  for (int r = 0; r < 4; ++r) {
    float p = 0.f;
    #pragma unroll
    for (int cb = 0; cb < 4; ++cb) {
      const float h = fmaxf(acc[cb][r] + b1v[cb], 0.f);
      p = fmaf(h, w2v[cb], p);
    }
    p += __shfl_xor(p, 1); p += __shfl_xor(p, 2);
    p += __shfl_xor(p, 4); p += __shfl_xor(p, 8);
    if ((ln & 15) == 0) scores[t0 + wv * 16 + 4 * (ln >> 4) + r] = p + b2v;
  }
}

// ---------------------------------------------------------------------------
// k_select: stats + exact top-64 via 4-pass radix select
// ---------------------------------------------------------------------------
__global__ __launch_bounds__(256) void k_select(
    const float* __restrict__ scores, int* __restrict__ top_idx,
    int* __restrict__ take_k)
{
  __shared__ float sS[N_];
  __shared__ u32 hist[256];
  __shared__ float redf[256];
  __shared__ u32 sPrefix, sRank, sCntA, sCntT;
  __shared__ int candIdx[64];
  __shared__ float candVal[64];
  __shared__ int tieIdx[128];
  const int b = blockIdx.x, tid = threadIdx.x;
  const float* s = scores + (size_t)b * N_;
  float sum = 0.f, sq = 0.f;
  for (int i = tid; i < N_; i += 256) {
    const float v = s[i]; sS[i] = v; sum += v; sq = fmaf(v, v, sq);
  }
  redf[tid] = sum; __syncthreads();
  for (int st = 128; st > 0; st >>= 1) { if (tid < st) redf[tid] += redf[tid + st]; __syncthreads(); }
  const float tot = redf[0]; __syncthreads();
  redf[tid] = sq; __syncthreads();
  for (int st = 128; st > 0; st >>= 1) { if (tid < st) redf[tid] += redf[tid + st]; __syncthreads(); }
  const float mean = tot / (float)N_;
  const float var = redf[0] / (float)N_ - mean * mean;
  const float thr = mean + 0.5f * sqrtf(fmaxf(var, 0.f));
  __syncthreads();
  int c = 0;
  for (int i = tid; i < N_; i += 256) c += (sS[i] > thr) ? 1 : 0;
  hist[tid] = (u32)c; __syncthreads();
  for (int st = 128; st > 0; st >>= 1) { if (tid < st) hist[tid] += hist[tid + st]; __syncthreads(); }
  if (tid == 0) {
    const int cnt = (int)hist[0];
    take_k[b] = (cnt == 0) ? M_ : (cnt < M_ ? cnt : M_);
  }
  __syncthreads();
  u32 prefix = 0, rank = 64, pmask = 0;
  for (int pass = 0; pass < 4; ++pass) {
    const int shift = 24 - 8 * pass;
    hist[tid] = 0;
    __syncthreads();
    for (int i = tid; i < N_; i += 256) {
      const u32 u = __float_as_uint(sS[i]);
      const u32 key = u ^ ((u32)((int)u >> 31) | 0x80000000u);
      if ((key & pmask) == prefix) atomicAdd(&hist[(key >> shift) & 255u], 1u);
    }
    __syncthreads();
    if (tid == 0) {
      u32 cum = 0;
      for (int cc = 255; cc >= 0; --cc) {
        cum += hist[cc];
        if (cum >= rank) {
          sPrefix = prefix | ((u32)cc << shift);
          sRank = rank - (cum - hist[cc]);
          break;
        }
      }
    }
    __syncthreads();
    prefix = sPrefix; rank = sRank;
    pmask |= 0xFFu << shift;
    __syncthreads();
  }
  if (tid == 0) { sCntA = 0; sCntT = 0; }
  __syncthreads();
  const u32 pivot = prefix;
  for (int i = tid; i < N_; i += 256) {
    const u32 u = __float_as_uint(sS[i]);
    const u32 key = u ^ ((u32)((int)u >> 31) | 0x80000000u);
    if (key > pivot) {
      const u32 p = atomicAdd(&sCntA, 1u);
      candIdx[p] = i; candVal[p] = sS[i];
    } else if (key == pivot) {
      const u32 p = atomicAdd(&sCntT, 1u);
      if (p < 128) tieIdx[p] = i;
    }
  }
  __syncthreads();
  if (tid == 0) {
    const int nA = (int)sCntA;
    const int need = 64 - nA;
    int nT = (int)sCntT; if (nT > 128) nT = 128;
    for (int j = 0; j < need; ++j) {
      int bi = 1 << 30, bp = -1;
      for (int q = 0; q < nT; ++q) {
        const int v = tieIdx[q];
        if (v >= 0 && v < bi) { bi = v; bp = q; }
      }
      candIdx[nA + j] = bi; candVal[nA + j] = sS[bi]; tieIdx[bp] = -1;
    }
  }
  __syncthreads();
  if (tid < 64) {
    const float v = candVal[tid]; const int ii = candIdx[tid];
    int rk = 0;
    for (int j = 0; j < 64; ++j) {
      const float vj = candVal[j]; const int ij = candIdx[j];
      rk += (vj > v || (vj == v && ij < ii)) ? 1 : 0;
    }
    top_idx[b * M_ + rk] = ii;
  }
}

// ---------------------------------------------------------------------------
// fragment loaders from fp32 LDS [64][65]
// ---------------------------------------------------------------------------
__device__ __forceinline__ bf16x8 ldsA_frag(const float (*S)[65], int wv, int kb, int ln) {
  const int lr = ln & 15;
  bf16x8 a;
  #pragma unroll
  for (int e = 0; e < 8; ++e) a[e] = (short)f2bf(S[16 * wv + lr][32 * kb + kslot(ln, e)]);
  return a;
}
__device__ __forceinline__ bf16x8 ldsB_frag(const float (*S)[65], int cb, int kb, int ln) {
  const int lr = ln & 15;
  bf16x8 bb;
  #pragma unroll
  for (int e = 0; e < 8; ++e) bb[e] = (short)f2bf(S[32 * kb + kslot(ln, e)][16 * cb + lr]);
  return bb;
}
__device__ __forceinline__ bf16x8 ldsBT_frag(const float (*S)[65], int cb, int kb, int ln) {
  const int lr = ln & 15;
  bf16x8 bb;
  #pragma unroll
  for (int e = 0; e < 8; ++e) bb[e] = (short)f2bf(S[16 * cb + lr][32 * kb + kslot(ln, e)]);
  return bb;
}

// ---------------------------------------------------------------------------
// k_graph: gather + H0 (K=512 MFMA) + cosine adjacency + 2-layer GCN, all MFMA
// one block per batch; emits Hg bf16 fragments (HgTf, Hgf)
// ---------------------------------------------------------------------------
__global__ __launch_bounds__(256) void k_graph(
    const float* __restrict__ X, const u16* __restrict__ t2nf,
    const u16* __restrict__ g1f, const u16* __restrict__ g2f,
    const int* __restrict__ top_idx, const int* __restrict__ take_k,
    u16* __restrict__ HgTf, u16* __restrict__ Hgf)
{
  __shared__ float sH0[64][65];
  __shared__ float sA[64][65];
  __shared__ float sT[64][65];
  __shared__ float sU[64][65];
  __shared__ float sR[64];
  const int b = blockIdx.x, tid = threadIdx.x;
  const int wv = tid >> 6, ln = tid & 63;
  const int lq = ln >> 4, lr = ln & 15;
  const int tk = take_k[b];
  const int rowm = 16 * wv + 4 * lq;  // D rows base for this lane

  // ---- H0 = gather(X) @ t2n (K=512), masked
  const int gidx = top_idx[b * M_ + 16 * wv + lr];
  const float* xr = X + ((size_t)b * N_ + gidx) * D_;
  f32x4 d[4];
  #pragma unroll
  for (int cb = 0; cb < 4; ++cb) d[cb] = (f32x4){0.f, 0.f, 0.f, 0.f};
  for (int kb = 0; kb < 16; ++kb) {
    const float4 v0 = *(const float4*)(xr + 32 * kb + 4 * lq);
    const float4 v1 = *(const float4*)(xr + 32 * kb + 16 + 4 * lq);
    bf16x8 a;
    a[0] = (short)f2bf(v0.x); a[1] = (short)f2bf(v0.y);
    a[2] = (short)f2bf(v0.z); a[3] = (short)f2bf(v0.w);
    a[4] = (short)f2bf(v1.x); a[5] = (short)f2bf(v1.y);
    a[6] = (short)f2bf(v1.z); a[7] = (short)f2bf(v1.w);
    #pragma unroll
    for (int cb = 0; cb < 4; ++cb) {
      const bf16x8 bb = *(const bf16x8*)&t2nf[(kb * 4 + cb) * 512 + ln * 8];
      d[cb] = __builtin_amdgcn_mfma_f32_16x16x32_bf16(a, bb, d[cb], 0, 0, 0);
    }
  }
  #pragma unroll
  for (int cb = 0; cb < 4; ++cb)
    #pragma unroll
    for (int r = 0; r < 4; ++r)
      sH0[rowm + r][16 * cb + lr] = (rowm + r < tk) ? d[cb][r] : 0.f;
  __syncthreads();

  // ---- norms -> inverse
  if (tid < 64) {
    float s = 0.f;
    #pragma unroll
    for (int k = 0; k < 64; ++k) { const float v = sH0[tid][k]; s = fmaf(v, v, s); }
    sR[tid] = 1.f / fmaxf(sqrtf(s), 1e-6f);
  }
  __syncthreads();
  // ---- Hn
  #pragma unroll
  for (int p = 0; p < 16; ++p) {
    const int o = tid + p * 256;
    const int i = o >> 6, k = o & 63;
    sU[i][k] = sH0[i][k] * sR[i];
  }
  __syncthreads();

  // ---- A = relu(Hn @ Hn^T), mask, +diag
  #pragma unroll
  for (int cb = 0; cb < 4; ++cb) d[cb] = (f32x4){0.f, 0.f, 0.f, 0.f};
  #pragma unroll
  for (int kb = 0; kb < 2; ++kb) {
    const bf16x8 a = ldsA_frag(sU, wv, kb, ln);
    #pragma unroll
    for (int cb = 0; cb < 4; ++cb)
      d[cb] = __builtin_amdgcn_mfma_f32_16x16x32_bf16(a, ldsBT_frag(sU, cb, kb, ln), d[cb], 0, 0, 0);
  }
  __syncthreads();
  #pragma unroll
  for (int cb = 0; cb < 4; ++cb)
    #pragma unroll
    for (int r = 0; r < 4; ++r) {
      const int row = rowm + r, col = 16 * cb + lr;
      float s = fmaxf(d[cb][r], 0.f);
      s = (row < tk && col < tk) ? s : 0.f;
      if (row == col && row < tk) s += 1.f;
      sA[row][col] = s;
    }
  __syncthreads();

  // ---- row-normalize A
  if (tid < 64) {
    float rs = 0.f;
    #pragma unroll
    for (int j = 0; j < 64; ++j) rs += sA[tid][j];
    sR[tid] = 1.f / fmaxf(rs, 1e-6f);
  }
  __syncthreads();
  #pragma unroll
  for (int p = 0; p < 16; ++p) {
    const int o = tid + p * 256;
    const int i = o >> 6, j = o & 63;
    sA[i][j] *= sR[i];
  }
  __syncthreads();

  // ---- T = A @ H0
  #pragma unroll
  for (int cb = 0; cb < 4; ++cb) d[cb] = (f32x4){0.f, 0.f, 0.f, 0.f};
  #pragma unroll
  for (int kb = 0; kb < 2; ++kb) {
    const bf16x8 a = ldsA_frag(sA, wv, kb, ln);
    #pragma unroll
    for (int cb = 0; cb < 4; ++cb)
      d[cb] = __builtin_amdgcn_mfma_f32_16x16x32_bf16(a, ldsB_frag(sH0, cb, kb, ln), d[cb], 0, 0, 0);
  }
  __syncthreads();
  #pragma unroll
  for (int cb = 0; cb < 4; ++cb)
    #pragma unroll
    for (int r = 0; r < 4; ++r) sT[rowm + r][16 * cb + lr] = d[cb][r];
  __syncthreads();

  // ---- X1 = relu(T @ g1)
  #pragma unroll
  for (int cb = 0; cb < 4; ++cb) d[cb] = (f32x4){0.f, 0.f, 0.f, 0.f};
  #pragma unroll
  for (int kb = 0; kb < 2; ++kb) {
    const bf16x8 a = ldsA_frag(sT, wv, kb, ln);
    #pragma unroll
    for (int cb = 0; cb < 4; ++cb) {
      const bf16x8 bb = *(const bf16x8*)&g1f[(kb * 4 + cb) * 512 + ln * 8];
      d[cb] = __builtin_amdgcn_mfma_f32_16x16x32_bf16(a, bb, d[cb], 0, 0, 0);
    }
  }
  __syncthreads();
  #pragma unroll
  for (int cb = 0; cb < 4; ++cb)
    #pragma unroll
    for (int r = 0; r < 4; ++r) sU[rowm + r][16 * cb + lr] = fmaxf(d[cb][r], 0.f);
  __syncthreads();

  // ---- T2 = A @ X1
  #pragma unroll
  for (int cb = 0; cb < 4; ++cb) d[cb] = (f32x4){0.f, 0.f, 0.f, 0.f};
  #pragma unroll
  for (int kb = 0; kb < 2; ++kb) {
    const bf16x8 a = ldsA_frag(sA, wv, kb, ln);
    #pragma unroll
    for (int cb = 0; cb < 4; ++cb)
      d[cb] = __builtin_amdgcn_mfma_f32_16x16x32_bf16(a, ldsB_frag(sU, cb, kb, ln), d[cb], 0, 0, 0);
  }
  __syncthreads();
  #pragma unroll
  for (int cb = 0; cb < 4; ++cb)
    #pragma unroll
    for (int r = 0; r < 4; ++r) sT[rowm + r][16 * cb + lr] = d[cb][r];
  __syncthreads();

  // ---- Hg = relu(T2 @ g2) -> bf16 fragments
  #pragma unroll
  for (int cb = 0; cb < 4; ++cb) d[cb] = (f32x4){0.f, 0.f, 0.f, 0.f};
  #pragma unroll
  for (int kb = 0; kb < 2; ++kb) {
    const bf16x8 a = ldsA_frag(sT, wv, kb, ln);
    #pragma unroll
    for (int cb = 0; cb < 4; ++cb) {
      const bf16x8 bb = *(const bf16x8*)&g2f[(kb * 4 + cb) * 512 + ln * 8];
      d[cb] = __builtin_amdgcn_mfma_f32_16x16x32_bf16(a, bb, d[cb], 0, 0, 0);
    }
  }
  #pragma unroll
  for (int cb = 0; cb < 4; ++cb)
    #pragma unroll
    for (int r = 0; r < 4; ++r) {
      const int node = rowm + r, feat = 16 * cb + lr;
      const u16 hb = f2bf(fmaxf(d[cb][r], 0.f));
      HgTf[(size_t)b * 4096 + bfrag_idx(feat, node, 4)] = hb;
      Hgf [(size_t)b * 4096 + bfrag_idx(node, feat, 4)] = hb;
    }
}

// ---------------------------------------------------------------------------
// k_attn: proj->logits->softmax->inject->back->residual, all GEMMs via MFMA
// ---------------------------------------------------------------------------
__global__ __launch_bounds__(256) void k_attn(
    const float* __restrict__ X, const u16* __restrict__ t2nf,
    const u16* __restrict__ n2tf, const u16* __restrict__ HgTf,
    const u16* __restrict__ Hgf, float* __restrict__ out)
{
  __shared__ __align__(16) u16 sAf[4096];
  const int tid = threadIdx.x;
  const int b = blockIdx.x >> 7;
  const int t0 = (blockIdx.x & 127) << 6;
  const float* Xb = X + (size_t)b * N_ * D_;
  float* Ob = out + (size_t)b * N_ * D_;
  const int wv = tid >> 6, ln = tid & 63;
  const int lq = ln >> 4, lr = ln & 15;

  // ---- P1: proj = X_tile @ t2n (K=512)
  f32x4 acc[4];
  #pragma unroll
  for (int cb = 0; cb < 4; ++cb) acc[cb] = (f32x4){0.f, 0.f, 0.f, 0.f};
  for (int ch = 0; ch < 8; ++ch) {
    __syncthreads();
    #pragma unroll
    for (int p = 0; p < 4; ++p) {
      const int i = tid + p * 256;
      const int row = i >> 4, k4 = i & 15;
      const float4 v = *(const float4*)(Xb + (size_t)(t0 + row) * D_ + ch * 64 + k4 * 4);
      const int idx = ((row >> 4) * 2 + (k4 >> 3)) * 512 +
                      ((row & 15) + 16 * (k4 & 3)) * 8 + 4 * ((k4 >> 2) & 1);
      *(uint2*)&sAf[idx] = make_uint2((u32)f2bf(v.x) | ((u32)f2bf(v.y) << 16),
                                      (u32)f2bf(v.z) | ((u32)f2bf(v.w) << 16));
    }
    __syncthreads();
    #pragma unroll
    for (int kb = 0; kb < 2; ++kb) {
      const bf16x8 a = *(const bf16x8*)&sAf[(wv * 2 + kb) * 512 + ln * 8];
      #pragma unroll
      for (int cb = 0; cb < 4; ++cb) {
        const bf16x8 bb = *(const bf16x8*)&t2nf[((ch * 2 + kb) * 4 + cb) * 512 + ln * 8];
        acc[cb] = __builtin_amdgcn_mfma_f32_16x16x32_bf16(a, bb, acc[cb], 0, 0, 0);
      }
    }
  }
  __syncthreads();
  #pragma unroll
  for (int cb = 0; cb < 4; ++cb)
    #pragma unroll
    for (int r = 0; r < 4; ++r) {
      const int col = 16 * cb + lr;
      const int idx = (wv * 2 + (col >> 5)) * 512 +
                      (4 * lq + r + 16 * ((col & 15) >> 2)) * 8 +
                      ((col & 3) + 4 * ((col >> 4) & 1));
      sAf[idx] = f2bf(acc[cb][r]);
    }
  __syncthreads();

  // ---- P2: logits = proj @ Hg^T (K=64)
  f32x4 accL[4];
  #pragma unroll
  for (int cb = 0; cb < 4; ++cb) accL[cb] = (f32x4){0.f, 0.f, 0.f, 0.f};
  #pragma unroll
  for (int kb = 0; kb < 2; ++kb) {
    const bf16x8 a = *(const bf16x8*)&sAf[(wv * 2 + kb) * 512 + ln * 8];
    #pragma unroll
    for (int cb = 0; cb < 4; ++cb) {
      const bf16x8 bb = *(const bf16x8*)&HgTf[(size_t)b * 4096 + (kb * 4 + cb) * 512 + ln * 8];
      accL[cb] = __builtin_amdgcn_mfma_f32_16x16x32_bf16(a, bb, accL[cb], 0, 0, 0);
    }
  }

  // ---- P3: softmax over m in registers
  float attnv[4][4];
  #pragma unroll
  for (int r = 0; r < 4; ++r) {
    const float v0 = accL[0][r], v1 = accL[1][r], v2 = accL[2][r], v3 = accL[3][r];
    float mx = fmaxf(fmaxf(v0, v1), fmaxf(v2, v3));
    mx = fmaxf(mx, __shfl_xor(mx, 1)); mx = fmaxf(mx, __shfl_xor(mx, 2));
    mx = fmaxf(mx, __shfl_xor(mx, 4)); mx = fmaxf(mx, __shfl_xor(mx, 8));
    const float e0 = __expf((v0 - mx) * 0.125f), e1 = __expf((v1 - mx) * 0.125f);
    const float e2 = __expf((v2 - mx) * 0.125f), e3 = __expf((v3 - mx) * 0.125f);
    float sm = (e0 + e1) + (e2 + e3);
    sm += __shfl_xor(sm, 1); sm += __shfl_xor(sm, 2);
    sm += __shfl_xor(sm, 4); sm += __shfl_xor(sm, 8);
    const float inv = 1.f / sm;
    attnv[0][r] = e0 * inv; attnv[1][r] = e1 * inv;
    attnv[2][r] = e2 * inv; attnv[3][r] = e3 * inv;
  }
  __syncthreads();
  #pragma unroll
  for (int cb = 0; cb < 4; ++cb)
    #pragma unroll
    for (int r = 0; r < 4; ++r) {
      const int col = 16 * cb + lr;
      const int idx = (wv * 2 + (col >> 5)) * 512 +
                      (4 * lq + r + 16 * ((col & 15) >> 2)) * 8 +
                      ((col & 3) + 4 * ((col >> 4) & 1));
      sAf[idx] = f2bf(attnv[cb][r]);
    }

  // ---- P5: inject = attn @ Hg (K=64)
  f32x4 accI[4];
  #pragma unroll
  for (int cb = 0; cb < 4; ++cb) accI[cb] = (f32x4){0.f, 0.f, 0.f, 0.f};
  #pragma unroll
  for (int kb = 0; kb < 2; ++kb) {
    const bf16x8 a = *(const bf16x8*)&sAf[(wv * 2 + kb) * 512 + ln * 8];
    #pragma unroll
    for (int cb = 0; cb < 4; ++cb) {
      const bf16x8 bb = *(const bf16x8*)&Hgf[(size_t)b * 4096 + (kb * 4 + cb) * 512 + ln * 8];
      accI[cb] = __builtin_amdgcn_mfma_f32_16x16x32_bf16(a, bb, accI[cb], 0, 0, 0);
    }
  }
  #pragma unroll
  for (int cb = 0; cb < 4; ++cb)
    #pragma unroll
    for (int r = 0; r < 4; ++r) {
      const int col = 16 * cb + lr;
      const int idx = (wv * 2 + (col >> 5)) * 512 +
                      (4 * lq + r + 16 * ((col & 15) >> 2)) * 8 +
                      ((col & 3) + 4 * ((col >> 4) & 1));
      sAf[idx] = f2bf(accI[cb][r]);
    }

  // ---- P7: back = inject @ n2t (K=64) + residual
  for (int chk = 0; chk < 4; ++chk) {
    f32x4 accB[8];
    #pragma unroll
    for (int c8 = 0; c8 < 8; ++c8) accB[c8] = (f32x4){0.f, 0.f, 0.f, 0.f};
    #pragma unroll
    for (int kb = 0; kb < 2; ++kb) {
      const bf16x8 a = *(const bf16x8*)&sAf[(wv * 2 + kb) * 512 + ln * 8];
      #pragma unroll
      for (int c8 = 0; c8 < 8; ++c8) {
        const int gcb = chk * 8 + c8;
        const bf16x8 bb = *(const bf16x8*)&n2tf[(kb * 32 + gcb) * 512 + ln * 8];
        accB[c8] = __builtin_amdgcn_mfma_f32_16x16x32_bf16(a, bb, accB[c8], 0, 0, 0);
      }
    }
    #pragma unroll
    for (int c8 = 0; c8 < 8; ++c8)
      #pragma unroll
      for (int r = 0; r < 4; ++r) {
        const int row = t0 + 16 * wv + 4 * lq + r;
        const int col = chk * 128 + 16 * c8 + lr;
        const size_t off = (size_t)row * D_ + col;
        Ob[off] = Xb[off] + accB[c8][r];
      }
  }
}

// ---------------------------------------------------------------------------
extern "C" void kernel_launch(void* const* d_in, const int* in_sizes, int n_in,
                              void* d_out, int out_size, void* d_ws, size_t ws_size,
                              hipStream_t stream)
{
  (void)in_sizes; (void)n_in; (void)out_size; (void)ws_size;
  const float* X   = (const float*)d_in[0];
  const float* W1  = (const float*)d_in[1];
  const float* b1  = (const float*)d_in[2];
  const float* w2  = (const float*)d_in[3];
  const float* b2  = (const float*)d_in[4];
  const float* t2n = (const float*)d_in[5];
  const float* n2t = (const float*)d_in[6];
  const float* g1  = (const float*)d_in[7];
  const float* g2  = (const float*)d_in[8];
  float* out = (float*)d_out;

  char* ws = (char*)d_ws;
  float* scores = (float*)(ws);                  // 256 KB
  u16* t2nf     = (u16*)(ws + 262144);           // 64 KB
  u16* n2tf     = (u16*)(ws + 327680);           // 64 KB
  u16* W1h      = (u16*)(ws + 393216);           // 64 KB
  u16* W1l      = (u16*)(ws + 458752);           // 64 KB
  u16* HgTf     = (u16*)(ws + 524288);           // 64 KB
  u16* Hgf      = (u16*)(ws + 589824);           // 64 KB
  u16* g1f      = (u16*)(ws + 655360);           // 8 KB
  u16* g2f      = (u16*)(ws + 663552);           // 8 KB
  int* top_idx  = (int*)(ws + 671744);           // 2 KB
  int* take_k   = (int*)(ws + 673792);           // 32 B

  k_prep<<<64, 256, 0, stream>>>(t2n, n2t, W1, g1, g2, t2nf, n2tf, W1h, W1l, g1f, g2f);
  k_scores<<<1024, 256, 0, stream>>>(X, W1h, W1l, b1, w2, b2, scores);
  k_select<<<B_, 256, 0, stream>>>(scores, top_idx, take_k);
  k_graph<<<B_, 256, 0, stream>>>(X, t2nf, g1f, g2f, top_idx, take_k, HgTf, Hgf);
  k_attn<<<1024, 256, 0, stream>>>(X, t2nf, n2tf, HgTf, Hgf, out);
}

// Round 4
// 201.083 us; speedup vs baseline: 3.0597x; 1.0046x over previous
//
#include <hip/hip_runtime.h>
#include <hip/hip_bf16.h>

#define B_ 8
#define N_ 8192
#define D_ 512
#define M_ 64

typedef unsigned short u16;
typedef unsigned int u32;
typedef __attribute__((ext_vector_type(8))) short bf16x8;
typedef __attribute__((ext_vector_type(4))) float f32x4;

__device__ __forceinline__ u16 f2bf(float f) {
  u32 u = __float_as_uint(f);
  u += 0x7FFFu + ((u >> 16) & 1u);
  return (u16)(u >> 16);
}
__device__ __forceinline__ float bf2f(u16 h) {
  return __uint_as_float(((u32)h) << 16);
}

// B-fragment index for matrix Mx[kd][c] with N cols: slot mapping shared by A.
__device__ __forceinline__ int bfrag_idx(int kd, int c, int ncols16) {
  int sub = (kd >> 5) * ncols16 + (c >> 4);
  int lane = (c & 15) + 16 * ((kd & 15) >> 2);
  int e = (kd & 3) + 4 * ((kd >> 4) & 1);
  return sub * 512 + lane * 8 + e;
}

// fragment k-slot for (lane, elem) within a 32-k block
__device__ __forceinline__ int kslot(int ln, int e) {
  return (e & 3) + 4 * (ln >> 4) + 16 * (e >> 2);
}

__device__ __forceinline__ bf16x8 pack8(float4 v0, float4 v1) {
  bf16x8 a;
  a[0] = (short)f2bf(v0.x); a[1] = (short)f2bf(v0.y);
  a[2] = (short)f2bf(v0.z); a[3] = (short)f2bf(v0.w);
  a[4] = (short)f2bf(v1.x); a[5] = (short)f2bf(v1.y);
  a[6] = (short)f2bf(v1.z); a[7] = (short)f2bf(v1.w);
  return a;
}

// ---------------------------------------------------------------------------
// k_prep: weights -> bf16 fragment layouts (t2n, n2t, W1 hi/lo, g1, g2)
// ---------------------------------------------------------------------------
__global__ __launch_bounds__(256) void k_prep(
    const float* __restrict__ t2n, const float* __restrict__ n2t,
    const float* __restrict__ W1, const float* __restrict__ g1,
    const float* __restrict__ g2,
    u16* __restrict__ t2nf, u16* __restrict__ n2tf,
    u16* __restrict__ W1h, u16* __restrict__ W1l,
    u16* __restrict__ g1f, u16* __restrict__ g2f)
{
  const int gid = blockIdx.x * 256 + threadIdx.x;
  const int stride = gridDim.x * 256;
  for (int s = gid; s < 512 * 64; s += stride) {
    const int k = s >> 6, c = s & 63;
    const int idx = bfrag_idx(k, c, 4);
    t2nf[idx] = f2bf(t2n[s]);
    const float w = W1[s];
    const u16 wh = f2bf(w);
    W1h[idx] = wh;
    W1l[idx] = f2bf(w - bf2f(wh));
  }
  for (int s = gid; s < 64 * 512; s += stride) {
    const int k = s >> 9, c = s & 511;
    n2tf[bfrag_idx(k, c, 32)] = f2bf(n2t[s]);
  }
  for (int s = gid; s < 4096; s += stride) {
    const int k = s >> 6, c = s & 63;
    g1f[bfrag_idx(k, c, 4)] = f2bf(g1[s]);
    g2f[bfrag_idx(k, c, 4)] = f2bf(g2[s]);
  }
}

// ---------------------------------------------------------------------------
// k_scores: scores = relu(X@W1+b1)@w2+b2, split-bf16 MFMA, zero LDS/barriers
// A-fragments loaded directly from global per wave (16 tokens each)
// ---------------------------------------------------------------------------
__global__ __launch_bounds__(256) void k_scores(
    const float* __restrict__ X, const u16* __restrict__ W1h,
    const u16* __restrict__ W1l, const float* __restrict__ b1,
    const float* __restrict__ w2, const float* __restrict__ b2,
    float* __restrict__ scores)
{
  const int tid = threadIdx.x;
  const int t0 = blockIdx.x * 64;
  const int wv = tid >> 6, ln = tid & 63;
  const int lq = ln >> 4, lr = ln & 15;
  const float* xr = X + (size_t)(t0 + 16 * wv + lr) * D_;

  f32x4 acc[4];
  #pragma unroll
  for (int cb = 0; cb < 4; ++cb) acc[cb] = (f32x4){0.f, 0.f, 0.f, 0.f};

  for (int kb = 0; kb < 16; ++kb) {
    const float4 v0 = *(const float4*)(xr + 32 * kb + 4 * lq);
    const float4 v1 = *(const float4*)(xr + 32 * kb + 16 + 4 * lq);
    const float xs[8] = {v0.x, v0.y, v0.z, v0.w, v1.x, v1.y, v1.z, v1.w};
    bf16x8 ah, al;
    #pragma unroll
    for (int e = 0; e < 8; ++e) {
      const u16 h = f2bf(xs[e]);
      ah[e] = (short)h;
      al[e] = (short)f2bf(xs[e] - bf2f(h));
    }
    #pragma unroll
    for (int cb = 0; cb < 4; ++cb) {
      const bf16x8 bh = *(const bf16x8*)&W1h[(kb * 4 + cb) * 512 + ln * 8];
      const bf16x8 bl = *(const bf16x8*)&W1l[(kb * 4 + cb) * 512 + ln * 8];
      acc[cb] = __builtin_amdgcn_mfma_f32_16x16x32_bf16(ah, bh, acc[cb], 0, 0, 0);
      acc[cb] = __builtin_amdgcn_mfma_f32_16x16x32_bf16(ah, bl, acc[cb], 0, 0, 0);
      acc[cb] = __builtin_amdgcn_mfma_f32_16x16x32_bf16(al, bh, acc[cb], 0, 0, 0);
    }
  }
  float b1v[4], w2v[4];
  #pragma unroll
  for (int cb = 0; cb < 4; ++cb) {
    const int col = cb * 16 + lr;
    b1v[cb] = b1[col]; w2v[cb] = w2[col];
  }
  const float b2v = b2[0];
  #pragma unroll
  for (int r = 0; r < 4; ++r) {
    float p = 0.f;
    #pragma unroll
    for (int cb = 0; cb < 4; ++cb) {
      const float h = fmaxf(acc[cb][r] + b1v[cb], 0.f);
      p = fmaf(h, w2v[cb], p);
    }
    p += __shfl_xor(p, 1); p += __shfl_xor(p, 2);
    p += __shfl_xor(p, 4); p += __shfl_xor(p, 8);
    if (lr == 0) scores[t0 + wv * 16 + 4 * lq + r] = p + b2v;
  }
}

// ---------------------------------------------------------------------------
// k_select: stats + exact top-64 via 4-pass radix select
// ---------------------------------------------------------------------------
__global__ __launch_bounds__(256) void k_select(
    const float* __restrict__ scores, int* __restrict__ top_idx,
    int* __restrict__ take_k)
{
  __shared__ float sS[N_];
  __shared__ u32 hist[256];
  __shared__ float redf[256];
  __shared__ u32 sPrefix, sRank, sCntA, sCntT;
  __shared__ int candIdx[64];
  __shared__ float candVal[64];
  __shared__ int tieIdx[128];
  const int b = blockIdx.x, tid = threadIdx.x;
  const float* s = scores + (size_t)b * N_;
  float sum = 0.f, sq = 0.f;
  for (int i = tid; i < N_; i += 256) {
    const float v = s[i]; sS[i] = v; sum += v; sq = fmaf(v, v, sq);
  }
  redf[tid] = sum; __syncthreads();
  for (int st = 128; st > 0; st >>= 1) { if (tid < st) redf[tid] += redf[tid + st]; __syncthreads(); }
  const float tot = redf[0]; __syncthreads();
  redf[tid] = sq; __syncthreads();
  for (int st = 128; st > 0; st >>= 1) { if (tid < st) redf[tid] += redf[tid + st]; __syncthreads(); }
  const float mean = tot / (float)N_;
  const float var = redf[0] / (float)N_ - mean * mean;
  const float thr = mean + 0.5f * sqrtf(fmaxf(var, 0.f));
  __syncthreads();
  int c = 0;
  for (int i = tid; i < N_; i += 256) c += (sS[i] > thr) ? 1 : 0;
  hist[tid] = (u32)c; __syncthreads();
  for (int st = 128; st > 0; st >>= 1) { if (tid < st) hist[tid] += hist[tid + st]; __syncthreads(); }
  if (tid == 0) {
    const int cnt = (int)hist[0];
    take_k[b] = (cnt == 0) ? M_ : (cnt < M_ ? cnt : M_);
  }
  __syncthreads();
  u32 prefix = 0, rank = 64, pmask = 0;
  for (int pass = 0; pass < 4; ++pass) {
    const int shift = 24 - 8 * pass;
    hist[tid] = 0;
    __syncthreads();
    for (int i = tid; i < N_; i += 256) {
      const u32 u = __float_as_uint(sS[i]);
      const u32 key = u ^ ((u32)((int)u >> 31) | 0x80000000u);
      if ((key & pmask) == prefix) atomicAdd(&hist[(key >> shift) & 255u], 1u);
    }
    __syncthreads();
    if (tid == 0) {
      u32 cum = 0;
      for (int cc = 255; cc >= 0; --cc) {
        cum += hist[cc];
        if (cum >= rank) {
          sPrefix = prefix | ((u32)cc << shift);
          sRank = rank - (cum - hist[cc]);
          break;
        }
      }
    }
    __syncthreads();
    prefix = sPrefix; rank = sRank;
    pmask |= 0xFFu << shift;
    __syncthreads();
  }
  if (tid == 0) { sCntA = 0; sCntT = 0; }
  __syncthreads();
  const u32 pivot = prefix;
  for (int i = tid; i < N_; i += 256) {
    const u32 u = __float_as_uint(sS[i]);
    const u32 key = u ^ ((u32)((int)u >> 31) | 0x80000000u);
    if (key > pivot) {
      const u32 p = atomicAdd(&sCntA, 1u);
      candIdx[p] = i; candVal[p] = sS[i];
    } else if (key == pivot) {
      const u32 p = atomicAdd(&sCntT, 1u);
      if (p < 128) tieIdx[p] = i;
    }
  }
  __syncthreads();
  if (tid == 0) {
    const int nA = (int)sCntA;
    const int need = 64 - nA;
    int nT = (int)sCntT; if (nT > 128) nT = 128;
    for (int j = 0; j < need; ++j) {
      int bi = 1 << 30, bp = -1;
      for (int q = 0; q < nT; ++q) {
        const int v = tieIdx[q];
        if (v >= 0 && v < bi) { bi = v; bp = q; }
      }
      candIdx[nA + j] = bi; candVal[nA + j] = sS[bi]; tieIdx[bp] = -1;
    }
  }
  __syncthreads();
  if (tid < 64) {
    const float v = candVal[tid]; const int ii = candIdx[tid];
    int rk = 0;
    for (int j = 0; j < 64; ++j) {
      const float vj = candVal[j]; const int ij = candIdx[j];
      rk += (vj > v || (vj == v && ij < ii)) ? 1 : 0;
    }
    top_idx[b * M_ + rk] = ii;
  }
}

// ---------------------------------------------------------------------------
// fragment loaders from fp32 LDS [64][65]
// ---------------------------------------------------------------------------
__device__ __forceinline__ bf16x8 ldsA_frag(const float (*S)[65], int wv, int kb, int ln) {
  const int lr = ln & 15;
  bf16x8 a;
  #pragma unroll
  for (int e = 0; e < 8; ++e) a[e] = (short)f2bf(S[16 * wv + lr][32 * kb + kslot(ln, e)]);
  return a;
}
__device__ __forceinline__ bf16x8 ldsB_frag(const float (*S)[65], int cb, int kb, int ln) {
  const int lr = ln & 15;
  bf16x8 bb;
  #pragma unroll
  for (int e = 0; e < 8; ++e) bb[e] = (short)f2bf(S[32 * kb + kslot(ln, e)][16 * cb + lr]);
  return bb;
}
__device__ __forceinline__ bf16x8 ldsBT_frag(const float (*S)[65], int cb, int kb, int ln) {
  const int lr = ln & 15;
  bf16x8 bb;
  #pragma unroll
  for (int e = 0; e < 8; ++e) bb[e] = (short)f2bf(S[16 * cb + lr][32 * kb + kslot(ln, e)]);
  return bb;
}

// ---------------------------------------------------------------------------
// k_graph: gather + H0 + cosine adjacency + 2-layer GCN + W = Hg@n2t
// one block per batch; emits HgTf (logits B) and Wf (back B) fragments
// ---------------------------------------------------------------------------
__global__ __launch_bounds__(256) void k_graph(
    const float* __restrict__ X, const u16* __restrict__ t2nf,
    const u16* __restrict__ n2tf, const u16* __restrict__ g1f,
    const u16* __restrict__ g2f, const int* __restrict__ top_idx,
    const int* __restrict__ take_k, u16* __restrict__ HgTf,
    u16* __restrict__ Wf)
{
  __shared__ float sH0[64][65];
  __shared__ float sA[64][65];
  __shared__ float sT[64][65];
  __shared__ float sU[64][65];
  __shared__ float sR[64];
  const int b = blockIdx.x, tid = threadIdx.x;
  const int wv = tid >> 6, ln = tid & 63;
  const int lq = ln >> 4, lr = ln & 15;
  const int tk = take_k[b];
  const int rowm = 16 * wv + 4 * lq;

  // ---- H0 = gather(X) @ t2n (K=512), masked
  const int gidx = top_idx[b * M_ + 16 * wv + lr];
  const float* xr = X + ((size_t)b * N_ + gidx) * D_;
  f32x4 d[4];
  #pragma unroll
  for (int cb = 0; cb < 4; ++cb) d[cb] = (f32x4){0.f, 0.f, 0.f, 0.f};
  for (int kb = 0; kb < 16; ++kb) {
    const float4 v0 = *(const float4*)(xr + 32 * kb + 4 * lq);
    const float4 v1 = *(const float4*)(xr + 32 * kb + 16 + 4 * lq);
    const bf16x8 a = pack8(v0, v1);
    #pragma unroll
    for (int cb = 0; cb < 4; ++cb) {
      const bf16x8 bb = *(const bf16x8*)&t2nf[(kb * 4 + cb) * 512 + ln * 8];
      d[cb] = __builtin_amdgcn_mfma_f32_16x16x32_bf16(a, bb, d[cb], 0, 0, 0);
    }
  }
  #pragma unroll
  for (int cb = 0; cb < 4; ++cb)
    #pragma unroll
    for (int r = 0; r < 4; ++r)
      sH0[rowm + r][16 * cb + lr] = (rowm + r < tk) ? d[cb][r] : 0.f;
  __syncthreads();

  // ---- norms -> inverse
  if (tid < 64) {
    float s = 0.f;
    #pragma unroll
    for (int k = 0; k < 64; ++k) { const float v = sH0[tid][k]; s = fmaf(v, v, s); }
    sR[tid] = 1.f / fmaxf(sqrtf(s), 1e-6f);
  }
  __syncthreads();
  #pragma unroll
  for (int p = 0; p < 16; ++p) {
    const int o = tid + p * 256;
    const int i = o >> 6, k = o & 63;
    sU[i][k] = sH0[i][k] * sR[i];
  }
  __syncthreads();

  // ---- A = relu(Hn @ Hn^T), mask, +diag
  #pragma unroll
  for (int cb = 0; cb < 4; ++cb) d[cb] = (f32x4){0.f, 0.f, 0.f, 0.f};
  #pragma unroll
  for (int kb = 0; kb < 2; ++kb) {
    const bf16x8 a = ldsA_frag(sU, wv, kb, ln);
    #pragma unroll
    for (int cb = 0; cb < 4; ++cb)
      d[cb] = __builtin_amdgcn_mfma_f32_16x16x32_bf16(a, ldsBT_frag(sU, cb, kb, ln), d[cb], 0, 0, 0);
  }
  __syncthreads();
  #pragma unroll
  for (int cb = 0; cb < 4; ++cb)
    #pragma unroll
    for (int r = 0; r < 4; ++r) {
      const int row = rowm + r, col = 16 * cb + lr;
      float s = fmaxf(d[cb][r], 0.f);
      s = (row < tk && col < tk) ? s : 0.f;
      if (row == col && row < tk) s += 1.f;
      sA[row][col] = s;
    }
  __syncthreads();

  // ---- row-normalize A
  if (tid < 64) {
    float rs = 0.f;
    #pragma unroll
    for (int j = 0; j < 64; ++j) rs += sA[tid][j];
    sR[tid] = 1.f / fmaxf(rs, 1e-6f);
  }
  __syncthreads();
  #pragma unroll
  for (int p = 0; p < 16; ++p) {
    const int o = tid + p * 256;
    const int i = o >> 6, j = o & 63;
    sA[i][j] *= sR[i];
  }
  __syncthreads();

  // ---- T = A @ H0
  #pragma unroll
  for (int cb = 0; cb < 4; ++cb) d[cb] = (f32x4){0.f, 0.f, 0.f, 0.f};
  #pragma unroll
  for (int kb = 0; kb < 2; ++kb) {
    const bf16x8 a = ldsA_frag(sA, wv, kb, ln);
    #pragma unroll
    for (int cb = 0; cb < 4; ++cb)
      d[cb] = __builtin_amdgcn_mfma_f32_16x16x32_bf16(a, ldsB_frag(sH0, cb, kb, ln), d[cb], 0, 0, 0);
  }
  __syncthreads();
  #pragma unroll
  for (int cb = 0; cb < 4; ++cb)
    #pragma unroll
    for (int r = 0; r < 4; ++r) sT[rowm + r][16 * cb + lr] = d[cb][r];
  __syncthreads();

  // ---- X1 = relu(T @ g1)
  #pragma unroll
  for (int cb = 0; cb < 4; ++cb) d[cb] = (f32x4){0.f, 0.f, 0.f, 0.f};
  #pragma unroll
  for (int kb = 0; kb < 2; ++kb) {
    const bf16x8 a = ldsA_frag(sT, wv, kb, ln);
    #pragma unroll
    for (int cb = 0; cb < 4; ++cb) {
      const bf16x8 bb = *(const bf16x8*)&g1f[(kb * 4 + cb) * 512 + ln * 8];
      d[cb] = __builtin_amdgcn_mfma_f32_16x16x32_bf16(a, bb, d[cb], 0, 0, 0);
    }
  }
  __syncthreads();
  #pragma unroll
  for (int cb = 0; cb < 4; ++cb)
    #pragma unroll
    for (int r = 0; r < 4; ++r) sU[rowm + r][16 * cb + lr] = fmaxf(d[cb][r], 0.f);
  __syncthreads();

  // ---- T2 = A @ X1
  #pragma unroll
  for (int cb = 0; cb < 4; ++cb) d[cb] = (f32x4){0.f, 0.f, 0.f, 0.f};
  #pragma unroll
  for (int kb = 0; kb < 2; ++kb) {
    const bf16x8 a = ldsA_frag(sA, wv, kb, ln);
    #pragma unroll
    for (int cb = 0; cb < 4; ++cb)
      d[cb] = __builtin_amdgcn_mfma_f32_16x16x32_bf16(a, ldsB_frag(sU, cb, kb, ln), d[cb], 0, 0, 0);
  }
  __syncthreads();
  #pragma unroll
  for (int cb = 0; cb < 4; ++cb)
    #pragma unroll
    for (int r = 0; r < 4; ++r) sT[rowm + r][16 * cb + lr] = d[cb][r];
  __syncthreads();

  // ---- Hg = relu(T2 @ g2) -> HgTf frags + LDS (for W matmul)
  #pragma unroll
  for (int cb = 0; cb < 4; ++cb) d[cb] = (f32x4){0.f, 0.f, 0.f, 0.f};
  #pragma unroll
  for (int kb = 0; kb < 2; ++kb) {
    const bf16x8 a = ldsA_frag(sT, wv, kb, ln);
    #pragma unroll
    for (int cb = 0; cb < 4; ++cb) {
      const bf16x8 bb = *(const bf16x8*)&g2f[(kb * 4 + cb) * 512 + ln * 8];
      d[cb] = __builtin_amdgcn_mfma_f32_16x16x32_bf16(a, bb, d[cb], 0, 0, 0);
    }
  }
  __syncthreads();
  #pragma unroll
  for (int cb = 0; cb < 4; ++cb)
    #pragma unroll
    for (int r = 0; r < 4; ++r) {
      const int node = rowm + r, feat = 16 * cb + lr;
      const float hv = fmaxf(d[cb][r], 0.f);
      HgTf[(size_t)b * 4096 + bfrag_idx(feat, node, 4)] = f2bf(hv);
      sU[node][feat] = hv;
    }
  __syncthreads();

  // ---- W = Hg @ n2t  [m=64][d=512] -> Wf B-frags (kd = m)
  for (int chk = 0; chk < 4; ++chk) {
    f32x4 aw[8];
    #pragma unroll
    for (int c8 = 0; c8 < 8; ++c8) aw[c8] = (f32x4){0.f, 0.f, 0.f, 0.f};
    #pragma unroll
    for (int kbf = 0; kbf < 2; ++kbf) {
      const bf16x8 a = ldsA_frag(sU, wv, kbf, ln);
      #pragma unroll
      for (int c8 = 0; c8 < 8; ++c8) {
        const bf16x8 bb = *(const bf16x8*)&n2tf[(kbf * 32 + chk * 8 + c8) * 512 + ln * 8];
        aw[c8] = __builtin_amdgcn_mfma_f32_16x16x32_bf16(a, bb, aw[c8], 0, 0, 0);
      }
    }
    #pragma unroll
    for (int c8 = 0; c8 < 8; ++c8)
      #pragma unroll
      for (int r = 0; r < 4; ++r) {
        const int m = 16 * wv + 4 * lq + r;
        const int c = (chk * 8 + c8) * 16 + lr;
        Wf[(size_t)b * 32768 + bfrag_idx(m, c, 32)] = f2bf(aw[c8][r]);
      }
  }
}

// ---------------------------------------------------------------------------
// k_attn: proj->logits->softmax->back(attn@W)->residual
// zero barriers: direct global A-frags + wave-local LDS bounce
// ---------------------------------------------------------------------------
__global__ __launch_bounds__(256) void k_attn(
    const float* __restrict__ X, const u16* __restrict__ t2nf,
    const u16* __restrict__ HgTf, const u16* __restrict__ Wf,
    float* __restrict__ out)
{
  __shared__ __align__(16) u16 sAf[4096];  // 4 waves x 1024 u16, wave-private
  const int tid = threadIdx.x;
  const int b = blockIdx.x >> 7;
  const int t0 = (blockIdx.x & 127) << 6;
  const float* Xb = X + (size_t)b * N_ * D_;
  float* Ob = out + (size_t)b * N_ * D_;
  const int wv = tid >> 6, ln = tid & 63;
  const int lq = ln >> 4, lr = ln & 15;
  u16* mySf = &sAf[wv * 1024];
  const float* xr = Xb + (size_t)(t0 + 16 * wv + lr) * D_;

  // ---- P1: proj = X_tile @ t2n (K=512), A-frags direct from global
  f32x4 acc[4];
  #pragma unroll
  for (int cb = 0; cb < 4; ++cb) acc[cb] = (f32x4){0.f, 0.f, 0.f, 0.f};
  for (int kb = 0; kb < 16; ++kb) {
    const float4 v0 = *(const float4*)(xr + 32 * kb + 4 * lq);
    const float4 v1 = *(const float4*)(xr + 32 * kb + 16 + 4 * lq);
    const bf16x8 a = pack8(v0, v1);
    #pragma unroll
    for (int cb = 0; cb < 4; ++cb) {
      const bf16x8 bb = *(const bf16x8*)&t2nf[(kb * 4 + cb) * 512 + ln * 8];
      acc[cb] = __builtin_amdgcn_mfma_f32_16x16x32_bf16(a, bb, acc[cb], 0, 0, 0);
    }
  }
  // D->A conversion, wave-private region (no block barrier needed)
  #pragma unroll
  for (int cb = 0; cb < 4; ++cb)
    #pragma unroll
    for (int r = 0; r < 4; ++r) {
      const int idx = (cb >> 1) * 512 + (4 * lq + r + 16 * (lr >> 2)) * 8 +
                      (lr & 3) + 4 * (cb & 1);
      mySf[idx] = f2bf(acc[cb][r]);
    }

  // ---- P2: logits = proj @ Hg^T (K=64)
  f32x4 accL[4];
  #pragma unroll
  for (int cb = 0; cb < 4; ++cb) accL[cb] = (f32x4){0.f, 0.f, 0.f, 0.f};
  #pragma unroll
  for (int kb = 0; kb < 2; ++kb) {
    const bf16x8 a = *(const bf16x8*)&mySf[kb * 512 + ln * 8];
    #pragma unroll
    for (int cb = 0; cb < 4; ++cb) {
      const bf16x8 bb = *(const bf16x8*)&HgTf[(size_t)b * 4096 + (kb * 4 + cb) * 512 + ln * 8];
      accL[cb] = __builtin_amdgcn_mfma_f32_16x16x32_bf16(a, bb, accL[cb], 0, 0, 0);
    }
  }

  // ---- P3: softmax over m in registers
  float attnv[4][4];
  #pragma unroll
  for (int r = 0; r < 4; ++r) {
    const float v0 = accL[0][r], v1 = accL[1][r], v2 = accL[2][r], v3 = accL[3][r];
    float mx = fmaxf(fmaxf(v0, v1), fmaxf(v2, v3));
    mx = fmaxf(mx, __shfl_xor(mx, 1)); mx = fmaxf(mx, __shfl_xor(mx, 2));
    mx = fmaxf(mx, __shfl_xor(mx, 4)); mx = fmaxf(mx, __shfl_xor(mx, 8));
    const float e0 = __expf((v0 - mx) * 0.125f), e1 = __expf((v1 - mx) * 0.125f);
    const float e2 = __expf((v2 - mx) * 0.125f), e3 = __expf((v3 - mx) * 0.125f);
    float sm = (e0 + e1) + (e2 + e3);
    sm += __shfl_xor(sm, 1); sm += __shfl_xor(sm, 2);
    sm += __shfl_xor(sm, 4); sm += __shfl_xor(sm, 8);
    const float inv = 1.f / sm;
    attnv[0][r] = e0 * inv; attnv[1][r] = e1 * inv;
    attnv[2][r] = e2 * inv; attnv[3][r] = e3 * inv;
  }
  // attn D->A, wave-private (proj frags fully consumed above)
  #pragma unroll
  for (int cb = 0; cb < 4; ++cb)
    #pragma unroll
    for (int r = 0; r < 4; ++r) {
      const int idx = (cb >> 1) * 512 + (4 * lq + r + 16 * (lr >> 2)) * 8 +
                      (lr & 3) + 4 * (cb & 1);
      mySf[idx] = f2bf(attnv[cb][r]);
    }

  // ---- P7: back = attn @ W (K=64, W = Hg@n2t precomputed) + residual
  for (int chk = 0; chk < 4; ++chk) {
    f32x4 accB[8];
    #pragma unroll
    for (int c8 = 0; c8 < 8; ++c8) accB[c8] = (f32x4){0.f, 0.f, 0.f, 0.f};
    #pragma unroll
    for (int kb = 0; kb < 2; ++kb) {
      const bf16x8 a = *(const bf16x8*)&mySf[kb * 512 + ln * 8];
      #pragma unroll
      for (int c8 = 0; c8 < 8; ++c8) {
        const bf16x8 bb = *(const bf16x8*)&Wf[(size_t)b * 32768 + (kb * 32 + chk * 8 + c8) * 512 + ln * 8];
        accB[c8] = __builtin_amdgcn_mfma_f32_16x16x32_bf16(a, bb, accB[c8], 0, 0, 0);
      }
    }
    #pragma unroll
    for (int c8 = 0; c8 < 8; ++c8)
      #pragma unroll
      for (int r = 0; r < 4; ++r) {
        const int row = t0 + 16 * wv + 4 * lq + r;
        const int col = chk * 128 + 16 * c8 + lr;
        const size_t off = (size_t)row * D_ + col;
        Ob[off] = Xb[off] + accB[c8][r];
      }
  }
}

// ---------------------------------------------------------------------------
extern "C" void kernel_launch(void* const* d_in, const int* in_sizes, int n_in,
                              void* d_out, int out_size, void* d_ws, size_t ws_size,
                              hipStream_t stream)
{
  (void)in_sizes; (void)n_in; (void)out_size; (void)ws_size;
  const float* X   = (const float*)d_in[0];
  const float* W1  = (const float*)d_in[1];
  const float* b1  = (const float*)d_in[2];
  const float* w2  = (const float*)d_in[3];
  const float* b2  = (const float*)d_in[4];
  const float* t2n = (const float*)d_in[5];
  const float* n2t = (const float*)d_in[6];
  const float* g1  = (const float*)d_in[7];
  const float* g2  = (const float*)d_in[8];
  float* out = (float*)d_out;

  char* ws = (char*)d_ws;
  float* scores = (float*)(ws);                  // 256 KB
  u16* t2nf     = (u16*)(ws + 262144);           // 64 KB
  u16* n2tf     = (u16*)(ws + 327680);           // 64 KB
  u16* W1h      = (u16*)(ws + 393216);           // 64 KB
  u16* W1l      = (u16*)(ws + 458752);           // 64 KB
  u16* HgTf     = (u16*)(ws + 524288);           // 64 KB
  u16* g1f      = (u16*)(ws + 589824);           // 8 KB
  u16* g2f      = (u16*)(ws + 598016);           // 8 KB
  int* top_idx  = (int*)(ws + 606208);           // 2 KB
  int* take_k   = (int*)(ws + 608256);           // 32 B
  u16* Wf       = (u16*)(ws + 609280);           // 512 KB

  k_prep<<<64, 256, 0, stream>>>(t2n, n2t, W1, g1, g2, t2nf, n2tf, W1h, W1l, g1f, g2f);
  k_scores<<<1024, 256, 0, stream>>>(X, W1h, W1l, b1, w2, b2, scores);
  k_select<<<B_, 256, 0, stream>>>(scores, top_idx, take_k);
  k_graph<<<B_, 256, 0, stream>>>(X, t2nf, n2tf, g1f, g2f, top_idx, take_k, HgTf, Wf);
  k_attn<<<1024, 256, 0, stream>>>(X, t2nf, HgTf, Wf, out);
}

// Round 5
// 185.836 us; speedup vs baseline: 3.3108x; 1.0820x over previous
//
#include <hip/hip_runtime.h>
#include <hip/hip_bf16.h>

#define B_ 8
#define N_ 8192
#define D_ 512
#define M_ 64

typedef unsigned short u16;
typedef unsigned int u32;
typedef __attribute__((ext_vector_type(8))) short bf16x8;
typedef __attribute__((ext_vector_type(4))) float f32x4;

__device__ __forceinline__ u16 f2bf(float f) {
  u32 u = __float_as_uint(f);
  u += 0x7FFFu + ((u >> 16) & 1u);
  return (u16)(u >> 16);
}
__device__ __forceinline__ float bf2f(u16 h) {
  return __uint_as_float(((u32)h) << 16);
}

// B-fragment index for matrix Mx[kd][c] with N cols: slot mapping shared by A.
__device__ __forceinline__ int bfrag_idx(int kd, int c, int ncols16) {
  int sub = (kd >> 5) * ncols16 + (c >> 4);
  int lane = (c & 15) + 16 * ((kd & 15) >> 2);
  int e = (kd & 3) + 4 * ((kd >> 4) & 1);
  return sub * 512 + lane * 8 + e;
}

// fragment k-slot for (lane, elem) within a 32-k block
__device__ __forceinline__ int kslot(int ln, int e) {
  return (e & 3) + 4 * (ln >> 4) + 16 * (e >> 2);
}

__device__ __forceinline__ bf16x8 pack8(float4 v0, float4 v1) {
  bf16x8 a;
  a[0] = (short)f2bf(v0.x); a[1] = (short)f2bf(v0.y);
  a[2] = (short)f2bf(v0.z); a[3] = (short)f2bf(v0.w);
  a[4] = (short)f2bf(v1.x); a[5] = (short)f2bf(v1.y);
  a[6] = (short)f2bf(v1.z); a[7] = (short)f2bf(v1.w);
  return a;
}

// ---------------------------------------------------------------------------
// k_prep: weights -> bf16 fragment layouts (t2n, n2t, W1 hi/lo, g1, g2)
// ---------------------------------------------------------------------------
__global__ __launch_bounds__(256) void k_prep(
    const float* __restrict__ t2n, const float* __restrict__ n2t,
    const float* __restrict__ W1, const float* __restrict__ g1,
    const float* __restrict__ g2,
    u16* __restrict__ t2nf, u16* __restrict__ n2tf,
    u16* __restrict__ W1h, u16* __restrict__ W1l,
    u16* __restrict__ g1f, u16* __restrict__ g2f)
{
  const int gid = blockIdx.x * 256 + threadIdx.x;
  const int stride = gridDim.x * 256;
  for (int s = gid; s < 512 * 64; s += stride) {
    const int k = s >> 6, c = s & 63;
    const int idx = bfrag_idx(k, c, 4);
    t2nf[idx] = f2bf(t2n[s]);
    const float w = W1[s];
    const u16 wh = f2bf(w);
    W1h[idx] = wh;
    W1l[idx] = f2bf(w - bf2f(wh));
  }
  for (int s = gid; s < 64 * 512; s += stride) {
    const int k = s >> 9, c = s & 511;
    n2tf[bfrag_idx(k, c, 32)] = f2bf(n2t[s]);
  }
  for (int s = gid; s < 4096; s += stride) {
    const int k = s >> 6, c = s & 63;
    g1f[bfrag_idx(k, c, 4)] = f2bf(g1[s]);
    g2f[bfrag_idx(k, c, 4)] = f2bf(g2[s]);
  }
}

// ---------------------------------------------------------------------------
// k_sp: FUSED scores + proj. One pass over X.
//   scores = relu(X@W1+b1)@w2+b2 (split-bf16, fp32-accurate)
//   proj   = X@t2n -> bf16 A-fragments stashed into d_out (tile's own rows)
// 16 MFMA per K-step on one load-pair. Zero block barriers.
// ---------------------------------------------------------------------------
__global__ __launch_bounds__(256) void k_sp(
    const float* __restrict__ X, const u16* __restrict__ W1h,
    const u16* __restrict__ W1l, const u16* __restrict__ t2nf,
    const float* __restrict__ b1, const float* __restrict__ w2,
    const float* __restrict__ b2, float* __restrict__ scores,
    float* __restrict__ outStash)
{
  __shared__ __align__(16) u16 sAf[4096];  // 4 waves x 1KB wave-private
  const int tid = threadIdx.x;
  const int t0 = blockIdx.x * 64;
  const int wv = tid >> 6, ln = tid & 63;
  const int lq = ln >> 4, lr = ln & 15;
  u16* mySf = &sAf[wv * 1024];
  const float* xr = X + (size_t)(t0 + 16 * wv + lr) * D_;

  f32x4 acc[4], accP[4];
  #pragma unroll
  for (int cb = 0; cb < 4; ++cb) {
    acc[cb] = (f32x4){0.f, 0.f, 0.f, 0.f};
    accP[cb] = (f32x4){0.f, 0.f, 0.f, 0.f};
  }

  for (int kb = 0; kb < 16; ++kb) {
    const float4 v0 = *(const float4*)(xr + 32 * kb + 4 * lq);
    const float4 v1 = *(const float4*)(xr + 32 * kb + 16 + 4 * lq);
    const float xs[8] = {v0.x, v0.y, v0.z, v0.w, v1.x, v1.y, v1.z, v1.w};
    bf16x8 ah, al;
    #pragma unroll
    for (int e = 0; e < 8; ++e) {
      const u16 h = f2bf(xs[e]);
      ah[e] = (short)h;
      al[e] = (short)f2bf(xs[e] - bf2f(h));
    }
    #pragma unroll
    for (int cb = 0; cb < 4; ++cb) {
      const bf16x8 bh = *(const bf16x8*)&W1h[(kb * 4 + cb) * 512 + ln * 8];
      const bf16x8 bl = *(const bf16x8*)&W1l[(kb * 4 + cb) * 512 + ln * 8];
      const bf16x8 bt = *(const bf16x8*)&t2nf[(kb * 4 + cb) * 512 + ln * 8];
      acc[cb] = __builtin_amdgcn_mfma_f32_16x16x32_bf16(ah, bh, acc[cb], 0, 0, 0);
      acc[cb] = __builtin_amdgcn_mfma_f32_16x16x32_bf16(ah, bl, acc[cb], 0, 0, 0);
      acc[cb] = __builtin_amdgcn_mfma_f32_16x16x32_bf16(al, bh, acc[cb], 0, 0, 0);
      accP[cb] = __builtin_amdgcn_mfma_f32_16x16x32_bf16(ah, bt, accP[cb], 0, 0, 0);
    }
  }

  // ---- scores epilogue
  float b1v[4], w2v[4];
  #pragma unroll
  for (int cb = 0; cb < 4; ++cb) {
    const int col = cb * 16 + lr;
    b1v[cb] = b1[col]; w2v[cb] = w2[col];
  }
  const float b2v = b2[0];
  #pragma unroll
  for (int r = 0; r < 4; ++r) {
    float p = 0.f;
    #pragma unroll
    for (int cb = 0; cb < 4; ++cb) {
      const float h = fmaxf(acc[cb][r] + b1v[cb], 0.f);
      p = fmaf(h, w2v[cb], p);
    }
    p += __shfl_xor(p, 1); p += __shfl_xor(p, 2);
    p += __shfl_xor(p, 4); p += __shfl_xor(p, 8);
    if (lr == 0) scores[t0 + wv * 16 + 4 * lq + r] = p + b2v;
  }

  // ---- proj D->A bounce (wave-private LDS) then coalesced 16B stash
  #pragma unroll
  for (int cb = 0; cb < 4; ++cb)
    #pragma unroll
    for (int r = 0; r < 4; ++r) {
      const int idx = (cb >> 1) * 512 + (4 * lq + r + 16 * (lr >> 2)) * 8 +
                      (lr & 3) + 4 * (cb & 1);
      mySf[idx] = f2bf(accP[cb][r]);
    }
  u16* stash = (u16*)(outStash + (size_t)blockIdx.x * 32768);
  #pragma unroll
  for (int kb2 = 0; kb2 < 2; ++kb2)
    *(bf16x8*)&stash[wv * 1024 + kb2 * 512 + ln * 8] =
        *(const bf16x8*)&mySf[kb2 * 512 + ln * 8];
}

// ---------------------------------------------------------------------------
// k_select: stats + exact top-64 via 4-pass radix select
// ---------------------------------------------------------------------------
__global__ __launch_bounds__(256) void k_select(
    const float* __restrict__ scores, int* __restrict__ top_idx,
    int* __restrict__ take_k)
{
  __shared__ float sS[N_];
  __shared__ u32 hist[256];
  __shared__ float redf[256];
  __shared__ u32 sPrefix, sRank, sCntA, sCntT;
  __shared__ int candIdx[64];
  __shared__ float candVal[64];
  __shared__ int tieIdx[128];
  const int b = blockIdx.x, tid = threadIdx.x;
  const float* s = scores + (size_t)b * N_;
  float sum = 0.f, sq = 0.f;
  for (int i = tid; i < N_; i += 256) {
    const float v = s[i]; sS[i] = v; sum += v; sq = fmaf(v, v, sq);
  }
  redf[tid] = sum; __syncthreads();
  for (int st = 128; st > 0; st >>= 1) { if (tid < st) redf[tid] += redf[tid + st]; __syncthreads(); }
  const float tot = redf[0]; __syncthreads();
  redf[tid] = sq; __syncthreads();
  for (int st = 128; st > 0; st >>= 1) { if (tid < st) redf[tid] += redf[tid + st]; __syncthreads(); }
  const float mean = tot / (float)N_;
  const float var = redf[0] / (float)N_ - mean * mean;
  const float thr = mean + 0.5f * sqrtf(fmaxf(var, 0.f));
  __syncthreads();
  int c = 0;
  for (int i = tid; i < N_; i += 256) c += (sS[i] > thr) ? 1 : 0;
  hist[tid] = (u32)c; __syncthreads();
  for (int st = 128; st > 0; st >>= 1) { if (tid < st) hist[tid] += hist[tid + st]; __syncthreads(); }
  if (tid == 0) {
    const int cnt = (int)hist[0];
    take_k[b] = (cnt == 0) ? M_ : (cnt < M_ ? cnt : M_);
  }
  __syncthreads();
  u32 prefix = 0, rank = 64, pmask = 0;
  for (int pass = 0; pass < 4; ++pass) {
    const int shift = 24 - 8 * pass;
    hist[tid] = 0;
    __syncthreads();
    for (int i = tid; i < N_; i += 256) {
      const u32 u = __float_as_uint(sS[i]);
      const u32 key = u ^ ((u32)((int)u >> 31) | 0x80000000u);
      if ((key & pmask) == prefix) atomicAdd(&hist[(key >> shift) & 255u], 1u);
    }
    __syncthreads();
    if (tid == 0) {
      u32 cum = 0;
      for (int cc = 255; cc >= 0; --cc) {
        cum += hist[cc];
        if (cum >= rank) {
          sPrefix = prefix | ((u32)cc << shift);
          sRank = rank - (cum - hist[cc]);
          break;
        }
      }
    }
    __syncthreads();
    prefix = sPrefix; rank = sRank;
    pmask |= 0xFFu << shift;
    __syncthreads();
  }
  if (tid == 0) { sCntA = 0; sCntT = 0; }
  __syncthreads();
  const u32 pivot = prefix;
  for (int i = tid; i < N_; i += 256) {
    const u32 u = __float_as_uint(sS[i]);
    const u32 key = u ^ ((u32)((int)u >> 31) | 0x80000000u);
    if (key > pivot) {
      const u32 p = atomicAdd(&sCntA, 1u);
      candIdx[p] = i; candVal[p] = sS[i];
    } else if (key == pivot) {
      const u32 p = atomicAdd(&sCntT, 1u);
      if (p < 128) tieIdx[p] = i;
    }
  }
  __syncthreads();
  if (tid == 0) {
    const int nA = (int)sCntA;
    const int need = 64 - nA;
    int nT = (int)sCntT; if (nT > 128) nT = 128;
    for (int j = 0; j < need; ++j) {
      int bi = 1 << 30, bp = -1;
      for (int q = 0; q < nT; ++q) {
        const int v = tieIdx[q];
        if (v >= 0 && v < bi) { bi = v; bp = q; }
      }
      candIdx[nA + j] = bi; candVal[nA + j] = sS[bi]; tieIdx[bp] = -1;
    }
  }
  __syncthreads();
  if (tid < 64) {
    const float v = candVal[tid]; const int ii = candIdx[tid];
    int rk = 0;
    for (int j = 0; j < 64; ++j) {
      const float vj = candVal[j]; const int ij = candIdx[j];
      rk += (vj > v || (vj == v && ij < ii)) ? 1 : 0;
    }
    top_idx[b * M_ + rk] = ii;
  }
}

// ---------------------------------------------------------------------------
// fragment loaders from fp32 LDS [64][65]
// ---------------------------------------------------------------------------
__device__ __forceinline__ bf16x8 ldsA_frag(const float (*S)[65], int wv, int kb, int ln) {
  const int lr = ln & 15;
  bf16x8 a;
  #pragma unroll
  for (int e = 0; e < 8; ++e) a[e] = (short)f2bf(S[16 * wv + lr][32 * kb + kslot(ln, e)]);
  return a;
}
__device__ __forceinline__ bf16x8 ldsB_frag(const float (*S)[65], int cb, int kb, int ln) {
  const int lr = ln & 15;
  bf16x8 bb;
  #pragma unroll
  for (int e = 0; e < 8; ++e) bb[e] = (short)f2bf(S[32 * kb + kslot(ln, e)][16 * cb + lr]);
  return bb;
}
__device__ __forceinline__ bf16x8 ldsBT_frag(const float (*S)[65], int cb, int kb, int ln) {
  const int lr = ln & 15;
  bf16x8 bb;
  #pragma unroll
  for (int e = 0; e < 8; ++e) bb[e] = (short)f2bf(S[16 * cb + lr][32 * kb + kslot(ln, e)]);
  return bb;
}

// ---------------------------------------------------------------------------
// k_graph: gather + H0 + cosine adjacency + 2-layer GCN + W = Hg@n2t
// one block per batch; emits HgTf (logits B) and Wf (back B) fragments
// ---------------------------------------------------------------------------
__global__ __launch_bounds__(256) void k_graph(
    const float* __restrict__ X, const u16* __restrict__ t2nf,
    const u16* __restrict__ n2tf, const u16* __restrict__ g1f,
    const u16* __restrict__ g2f, const int* __restrict__ top_idx,
    const int* __restrict__ take_k, u16* __restrict__ HgTf,
    u16* __restrict__ Wf)
{
  __shared__ float sH0[64][65];
  __shared__ float sA[64][65];
  __shared__ float sT[64][65];
  __shared__ float sU[64][65];
  __shared__ float sR[64];
  const int b = blockIdx.x, tid = threadIdx.x;
  const int wv = tid >> 6, ln = tid & 63;
  const int lq = ln >> 4, lr = ln & 15;
  const int tk = take_k[b];
  const int rowm = 16 * wv + 4 * lq;

  // ---- H0 = gather(X) @ t2n (K=512), masked
  const int gidx = top_idx[b * M_ + 16 * wv + lr];
  const float* xr = X + ((size_t)b * N_ + gidx) * D_;
  f32x4 d[4];
  #pragma unroll
  for (int cb = 0; cb < 4; ++cb) d[cb] = (f32x4){0.f, 0.f, 0.f, 0.f};
  for (int kb = 0; kb < 16; ++kb) {
    const float4 v0 = *(const float4*)(xr + 32 * kb + 4 * lq);
    const float4 v1 = *(const float4*)(xr + 32 * kb + 16 + 4 * lq);
    const bf16x8 a = pack8(v0, v1);
    #pragma unroll
    for (int cb = 0; cb < 4; ++cb) {
      const bf16x8 bb = *(const bf16x8*)&t2nf[(kb * 4 + cb) * 512 + ln * 8];
      d[cb] = __builtin_amdgcn_mfma_f32_16x16x32_bf16(a, bb, d[cb], 0, 0, 0);
    }
  }
  #pragma unroll
  for (int cb = 0; cb < 4; ++cb)
    #pragma unroll
    for (int r = 0; r < 4; ++r)
      sH0[rowm + r][16 * cb + lr] = (rowm + r < tk) ? d[cb][r] : 0.f;
  __syncthreads();

  // ---- norms -> inverse
  if (tid < 64) {
    float s = 0.f;
    #pragma unroll
    for (int k = 0; k < 64; ++k) { const float v = sH0[tid][k]; s = fmaf(v, v, s); }
    sR[tid] = 1.f / fmaxf(sqrtf(s), 1e-6f);
  }
  __syncthreads();
  #pragma unroll
  for (int p = 0; p < 16; ++p) {
    const int o = tid + p * 256;
    const int i = o >> 6, k = o & 63;
    sU[i][k] = sH0[i][k] * sR[i];
  }
  __syncthreads();

  // ---- A = relu(Hn @ Hn^T), mask, +diag
  #pragma unroll
  for (int cb = 0; cb < 4; ++cb) d[cb] = (f32x4){0.f, 0.f, 0.f, 0.f};
  #pragma unroll
  for (int kb = 0; kb < 2; ++kb) {
    const bf16x8 a = ldsA_frag(sU, wv, kb, ln);
    #pragma unroll
    for (int cb = 0; cb < 4; ++cb)
      d[cb] = __builtin_amdgcn_mfma_f32_16x16x32_bf16(a, ldsBT_frag(sU, cb, kb, ln), d[cb], 0, 0, 0);
  }
  __syncthreads();
  #pragma unroll
  for (int cb = 0; cb < 4; ++cb)
    #pragma unroll
    for (int r = 0; r < 4; ++r) {
      const int row = rowm + r, col = 16 * cb + lr;
      float s = fmaxf(d[cb][r], 0.f);
      s = (row < tk && col < tk) ? s : 0.f;
      if (row == col && row < tk) s += 1.f;
      sA[row][col] = s;
    }
  __syncthreads();

  // ---- row-normalize A
  if (tid < 64) {
    float rs = 0.f;
    #pragma unroll
    for (int j = 0; j < 64; ++j) rs += sA[tid][j];
    sR[tid] = 1.f / fmaxf(rs, 1e-6f);
  }
  __syncthreads();
  #pragma unroll
  for (int p = 0; p < 16; ++p) {
    const int o = tid + p * 256;
    const int i = o >> 6, j = o & 63;
    sA[i][j] *= sR[i];
  }
  __syncthreads();

  // ---- T = A @ H0
  #pragma unroll
  for (int cb = 0; cb < 4; ++cb) d[cb] = (f32x4){0.f, 0.f, 0.f, 0.f};
  #pragma unroll
  for (int kb = 0; kb < 2; ++kb) {
    const bf16x8 a = ldsA_frag(sA, wv, kb, ln);
    #pragma unroll
    for (int cb = 0; cb < 4; ++cb)
      d[cb] = __builtin_amdgcn_mfma_f32_16x16x32_bf16(a, ldsB_frag(sH0, cb, kb, ln), d[cb], 0, 0, 0);
  }
  __syncthreads();
  #pragma unroll
  for (int cb = 0; cb < 4; ++cb)
    #pragma unroll
    for (int r = 0; r < 4; ++r) sT[rowm + r][16 * cb + lr] = d[cb][r];
  __syncthreads();

  // ---- X1 = relu(T @ g1)
  #pragma unroll
  for (int cb = 0; cb < 4; ++cb) d[cb] = (f32x4){0.f, 0.f, 0.f, 0.f};
  #pragma unroll
  for (int kb = 0; kb < 2; ++kb) {
    const bf16x8 a = ldsA_frag(sT, wv, kb, ln);
    #pragma unroll
    for (int cb = 0; cb < 4; ++cb) {
      const bf16x8 bb = *(const bf16x8*)&g1f[(kb * 4 + cb) * 512 + ln * 8];
      d[cb] = __builtin_amdgcn_mfma_f32_16x16x32_bf16(a, bb, d[cb], 0, 0, 0);
    }
  }
  __syncthreads();
  #pragma unroll
  for (int cb = 0; cb < 4; ++cb)
    #pragma unroll
    for (int r = 0; r < 4; ++r) sU[rowm + r][16 * cb + lr] = fmaxf(d[cb][r], 0.f);
  __syncthreads();

  // ---- T2 = A @ X1
  #pragma unroll
  for (int cb = 0; cb < 4; ++cb) d[cb] = (f32x4){0.f, 0.f, 0.f, 0.f};
  #pragma unroll
  for (int kb = 0; kb < 2; ++kb) {
    const bf16x8 a = ldsA_frag(sA, wv, kb, ln);
    #pragma unroll
    for (int cb = 0; cb < 4; ++cb)
      d[cb] = __builtin_amdgcn_mfma_f32_16x16x32_bf16(a, ldsB_frag(sU, cb, kb, ln), d[cb], 0, 0, 0);
  }
  __syncthreads();
  #pragma unroll
  for (int cb = 0; cb < 4; ++cb)
    #pragma unroll
    for (int r = 0; r < 4; ++r) sT[rowm + r][16 * cb + lr] = d[cb][r];
  __syncthreads();

  // ---- Hg = relu(T2 @ g2) -> HgTf frags + LDS (for W matmul)
  #pragma unroll
  for (int cb = 0; cb < 4; ++cb) d[cb] = (f32x4){0.f, 0.f, 0.f, 0.f};
  #pragma unroll
  for (int kb = 0; kb < 2; ++kb) {
    const bf16x8 a = ldsA_frag(sT, wv, kb, ln);
    #pragma unroll
    for (int cb = 0; cb < 4; ++cb) {
      const bf16x8 bb = *(const bf16x8*)&g2f[(kb * 4 + cb) * 512 + ln * 8];
      d[cb] = __builtin_amdgcn_mfma_f32_16x16x32_bf16(a, bb, d[cb], 0, 0, 0);
    }
  }
  __syncthreads();
  #pragma unroll
  for (int cb = 0; cb < 4; ++cb)
    #pragma unroll
    for (int r = 0; r < 4; ++r) {
      const int node = rowm + r, feat = 16 * cb + lr;
      const float hv = fmaxf(d[cb][r], 0.f);
      HgTf[(size_t)b * 4096 + bfrag_idx(feat, node, 4)] = f2bf(hv);
      sU[node][feat] = hv;
    }
  __syncthreads();

  // ---- W = Hg @ n2t  [m=64][d=512] -> Wf B-frags (kd = m)
  for (int chk = 0; chk < 4; ++chk) {
    f32x4 aw[8];
    #pragma unroll
    for (int c8 = 0; c8 < 8; ++c8) aw[c8] = (f32x4){0.f, 0.f, 0.f, 0.f};
    #pragma unroll
    for (int kbf = 0; kbf < 2; ++kbf) {
      const bf16x8 a = ldsA_frag(sU, wv, kbf, ln);
      #pragma unroll
      for (int c8 = 0; c8 < 8; ++c8) {
        const bf16x8 bb = *(const bf16x8*)&n2tf[(kbf * 32 + chk * 8 + c8) * 512 + ln * 8];
        aw[c8] = __builtin_amdgcn_mfma_f32_16x16x32_bf16(a, bb, aw[c8], 0, 0, 0);
      }
    }
    #pragma unroll
    for (int c8 = 0; c8 < 8; ++c8)
      #pragma unroll
      for (int r = 0; r < 4; ++r) {
        const int m = 16 * wv + 4 * lq + r;
        const int c = (chk * 8 + c8) * 16 + lr;
        Wf[(size_t)b * 32768 + bfrag_idx(m, c, 32)] = f2bf(aw[c8][r]);
      }
  }
}

// ---------------------------------------------------------------------------
// k_attn: logits(from stashed proj frags)->softmax->back(attn@W)->residual
// X is touched only by the residual stream. Zero block barriers.
// ---------------------------------------------------------------------------
__global__ __launch_bounds__(256) void k_attn(
    const float* __restrict__ X, const u16* __restrict__ HgTf,
    const u16* __restrict__ Wf, float* __restrict__ out)
{
  __shared__ __align__(16) u16 sAf[4096];  // 4 waves x 1KB wave-private
  const int tid = threadIdx.x;
  const int b = blockIdx.x >> 7;
  const int t0 = (blockIdx.x & 127) << 6;
  const float* Xb = X + (size_t)b * N_ * D_;
  float* Ob = out + (size_t)b * N_ * D_;
  const int wv = tid >> 6, ln = tid & 63;
  const int lq = ln >> 4, lr = ln & 15;
  u16* mySf = &sAf[wv * 1024];
  const u16* stash = (const u16*)(out + (size_t)blockIdx.x * 32768);

  // ---- P2: logits = proj @ Hg^T (K=64); proj A-frags read from stash
  f32x4 accL[4];
  #pragma unroll
  for (int cb = 0; cb < 4; ++cb) accL[cb] = (f32x4){0.f, 0.f, 0.f, 0.f};
  #pragma unroll
  for (int kb = 0; kb < 2; ++kb) {
    const bf16x8 a = *(const bf16x8*)&stash[wv * 1024 + kb * 512 + ln * 8];
    #pragma unroll
    for (int cb = 0; cb < 4; ++cb) {
      const bf16x8 bb = *(const bf16x8*)&HgTf[(size_t)b * 4096 + (kb * 4 + cb) * 512 + ln * 8];
      accL[cb] = __builtin_amdgcn_mfma_f32_16x16x32_bf16(a, bb, accL[cb], 0, 0, 0);
    }
  }

  // ---- P3: softmax over m in registers
  float attnv[4][4];
  #pragma unroll
  for (int r = 0; r < 4; ++r) {
    const float v0 = accL[0][r], v1 = accL[1][r], v2 = accL[2][r], v3 = accL[3][r];
    float mx = fmaxf(fmaxf(v0, v1), fmaxf(v2, v3));
    mx = fmaxf(mx, __shfl_xor(mx, 1)); mx = fmaxf(mx, __shfl_xor(mx, 2));
    mx = fmaxf(mx, __shfl_xor(mx, 4)); mx = fmaxf(mx, __shfl_xor(mx, 8));
    const float e0 = __expf((v0 - mx) * 0.125f), e1 = __expf((v1 - mx) * 0.125f);
    const float e2 = __expf((v2 - mx) * 0.125f), e3 = __expf((v3 - mx) * 0.125f);
    float sm = (e0 + e1) + (e2 + e3);
    sm += __shfl_xor(sm, 1); sm += __shfl_xor(sm, 2);
    sm += __shfl_xor(sm, 4); sm += __shfl_xor(sm, 8);
    const float inv = 1.f / sm;
    attnv[0][r] = e0 * inv; attnv[1][r] = e1 * inv;
    attnv[2][r] = e2 * inv; attnv[3][r] = e3 * inv;
  }
  // attn D->A bounce, wave-private
  #pragma unroll
  for (int cb = 0; cb < 4; ++cb)
    #pragma unroll
    for (int r = 0; r < 4; ++r) {
      const int idx = (cb >> 1) * 512 + (4 * lq + r + 16 * (lr >> 2)) * 8 +
                      (lr & 3) + 4 * (cb & 1);
      mySf[idx] = f2bf(attnv[cb][r]);
    }

  // ---- P7: back = attn @ W (K=64, W = Hg@n2t) + residual stream
  for (int chk = 0; chk < 4; ++chk) {
    f32x4 accB[8];
    #pragma unroll
    for (int c8 = 0; c8 < 8; ++c8) accB[c8] = (f32x4){0.f, 0.f, 0.f, 0.f};
    #pragma unroll
    for (int kb = 0; kb < 2; ++kb) {
      const bf16x8 a = *(const bf16x8*)&mySf[kb * 512 + ln * 8];
      #pragma unroll
      for (int c8 = 0; c8 < 8; ++c8) {
        const bf16x8 bb = *(const bf16x8*)&Wf[(size_t)b * 32768 + (kb * 32 + chk * 8 + c8) * 512 + ln * 8];
        accB[c8] = __builtin_amdgcn_mfma_f32_16x16x32_bf16(a, bb, accB[c8], 0, 0, 0);
      }
    }
    #pragma unroll
    for (int c8 = 0; c8 < 8; ++c8)
      #pragma unroll
      for (int r = 0; r < 4; ++r) {
        const int row = t0 + 16 * wv + 4 * lq + r;
        const int col = chk * 128 + 16 * c8 + lr;
        const size_t off = (size_t)row * D_ + col;
        Ob[off] = Xb[off] + accB[c8][r];
      }
  }
}

// ---------------------------------------------------------------------------
extern "C" void kernel_launch(void* const* d_in, const int* in_sizes, int n_in,
                              void* d_out, int out_size, void* d_ws, size_t ws_size,
                              hipStream_t stream)
{
  (void)in_sizes; (void)n_in; (void)out_size; (void)ws_size;
  const float* X   = (const float*)d_in[0];
  const float* W1  = (const float*)d_in[1];
  const float* b1  = (const float*)d_in[2];
  const float* w2  = (const float*)d_in[3];
  const float* b2  = (const float*)d_in[4];
  const float* t2n = (const float*)d_in[5];
  const float* n2t = (const float*)d_in[6];
  const float* g1  = (const float*)d_in[7];
  const float* g2  = (const float*)d_in[8];
  float* out = (float*)d_out;

  char* ws = (char*)d_ws;
  float* scores = (float*)(ws);                  // 256 KB
  u16* t2nf     = (u16*)(ws + 262144);           // 64 KB
  u16* n2tf     = (u16*)(ws + 327680);           // 64 KB
  u16* W1h      = (u16*)(ws + 393216);           // 64 KB
  u16* W1l      = (u16*)(ws + 458752);           // 64 KB
  u16* HgTf     = (u16*)(ws + 524288);           // 64 KB
  u16* g1f      = (u16*)(ws + 589824);           // 8 KB
  u16* g2f      = (u16*)(ws + 598016);           // 8 KB
  int* top_idx  = (int*)(ws + 606208);           // 2 KB
  int* take_k   = (int*)(ws + 608256);           // 32 B
  u16* Wf       = (u16*)(ws + 609280);           // 512 KB

  k_prep<<<64, 256, 0, stream>>>(t2n, n2t, W1, g1, g2, t2nf, n2tf, W1h, W1l, g1f, g2f);
  k_sp<<<1024, 256, 0, stream>>>(X, W1h, W1l, t2nf, b1, w2, b2, scores, out);
  k_select<<<B_, 256, 0, stream>>>(scores, top_idx, take_k);
  k_graph<<<B_, 256, 0, stream>>>(X, t2nf, n2tf, g1f, g2f, top_idx, take_k, HgTf, Wf);
  k_attn<<<1024, 256, 0, stream>>>(X, HgTf, Wf, out);
}

// Round 6
// 175.217 us; speedup vs baseline: 3.5114x; 1.0606x over previous
//
#include <hip/hip_runtime.h>
#include <hip/hip_bf16.h>

#define B_ 8
#define N_ 8192
#define D_ 512
#define M_ 64

typedef unsigned short u16;
typedef unsigned int u32;
typedef __attribute__((ext_vector_type(8))) short bf16x8;
typedef __attribute__((ext_vector_type(4))) float f32x4;

__device__ __forceinline__ u16 f2bf(float f) {
  u32 u = __float_as_uint(f);
  u += 0x7FFFu + ((u >> 16) & 1u);
  return (u16)(u >> 16);
}
__device__ __forceinline__ float bf2f(u16 h) {
  return __uint_as_float(((u32)h) << 16);
}

// B-fragment index for matrix Mx[kd][c] with N cols: slot mapping shared by A.
__device__ __forceinline__ int bfrag_idx(int kd, int c, int ncols16) {
  int sub = (kd >> 5) * ncols16 + (c >> 4);
  int lane = (c & 15) + 16 * ((kd & 15) >> 2);
  int e = (kd & 3) + 4 * ((kd >> 4) & 1);
  return sub * 512 + lane * 8 + e;
}

// fragment k-slot for (lane, elem) within a 32-k block
__device__ __forceinline__ int kslot(int ln, int e) {
  return (e & 3) + 4 * (ln >> 4) + 16 * (e >> 2);
}

__device__ __forceinline__ bf16x8 pack8(float4 v0, float4 v1) {
  bf16x8 a;
  a[0] = (short)f2bf(v0.x); a[1] = (short)f2bf(v0.y);
  a[2] = (short)f2bf(v0.z); a[3] = (short)f2bf(v0.w);
  a[4] = (short)f2bf(v1.x); a[5] = (short)f2bf(v1.y);
  a[6] = (short)f2bf(v1.z); a[7] = (short)f2bf(v1.w);
  return a;
}

// ---------------------------------------------------------------------------
// k_prep: weights -> bf16 fragment layouts (t2n, n2t, W1 hi/lo, g1, g2)
// ---------------------------------------------------------------------------
__global__ __launch_bounds__(256) void k_prep(
    const float* __restrict__ t2n, const float* __restrict__ n2t,
    const float* __restrict__ W1, const float* __restrict__ g1,
    const float* __restrict__ g2,
    u16* __restrict__ t2nf, u16* __restrict__ n2tf,
    u16* __restrict__ W1h, u16* __restrict__ W1l,
    u16* __restrict__ g1f, u16* __restrict__ g2f)
{
  const int gid = blockIdx.x * 256 + threadIdx.x;
  const int stride = gridDim.x * 256;
  for (int s = gid; s < 512 * 64; s += stride) {
    const int k = s >> 6, c = s & 63;
    const int idx = bfrag_idx(k, c, 4);
    t2nf[idx] = f2bf(t2n[s]);
    const float w = W1[s];
    const u16 wh = f2bf(w);
    W1h[idx] = wh;
    W1l[idx] = f2bf(w - bf2f(wh));
  }
  for (int s = gid; s < 64 * 512; s += stride) {
    const int k = s >> 9, c = s & 511;
    n2tf[bfrag_idx(k, c, 32)] = f2bf(n2t[s]);
  }
  for (int s = gid; s < 4096; s += stride) {
    const int k = s >> 6, c = s & 63;
    g1f[bfrag_idx(k, c, 4)] = f2bf(g1[s]);
    g2f[bfrag_idx(k, c, 4)] = f2bf(g2[s]);
  }
}

// ---------------------------------------------------------------------------
// k_sp: FUSED scores + proj. One pass over X, A-tile prefetch by one K-step.
// ---------------------------------------------------------------------------
__global__ __launch_bounds__(256) void k_sp(
    const float* __restrict__ X, const u16* __restrict__ W1h,
    const u16* __restrict__ W1l, const u16* __restrict__ t2nf,
    const float* __restrict__ b1, const float* __restrict__ w2,
    const float* __restrict__ b2, float* __restrict__ scores,
    float* __restrict__ outStash)
{
  __shared__ __align__(16) u16 sAf[4096];  // 4 waves x 1KB wave-private
  const int tid = threadIdx.x;
  const int t0 = blockIdx.x * 64;
  const int wv = tid >> 6, ln = tid & 63;
  const int lq = ln >> 4, lr = ln & 15;
  u16* mySf = &sAf[wv * 1024];
  const float* xr = X + (size_t)(t0 + 16 * wv + lr) * D_;

  f32x4 acc[4], accP[4];
  #pragma unroll
  for (int cb = 0; cb < 4; ++cb) {
    acc[cb] = (f32x4){0.f, 0.f, 0.f, 0.f};
    accP[cb] = (f32x4){0.f, 0.f, 0.f, 0.f};
  }

  float4 v0 = *(const float4*)(xr + 4 * lq);
  float4 v1 = *(const float4*)(xr + 16 + 4 * lq);
  for (int kb = 0; kb < 16; ++kb) {
    float4 n0 = v0, n1 = v1;
    if (kb < 15) {
      n0 = *(const float4*)(xr + 32 * (kb + 1) + 4 * lq);
      n1 = *(const float4*)(xr + 32 * (kb + 1) + 16 + 4 * lq);
    }
    const float xs[8] = {v0.x, v0.y, v0.z, v0.w, v1.x, v1.y, v1.z, v1.w};
    bf16x8 ah, al;
    #pragma unroll
    for (int e = 0; e < 8; ++e) {
      const u16 h = f2bf(xs[e]);
      ah[e] = (short)h;
      al[e] = (short)f2bf(xs[e] - bf2f(h));
    }
    #pragma unroll
    for (int cb = 0; cb < 4; ++cb) {
      const bf16x8 bh = *(const bf16x8*)&W1h[(kb * 4 + cb) * 512 + ln * 8];
      const bf16x8 bl = *(const bf16x8*)&W1l[(kb * 4 + cb) * 512 + ln * 8];
      const bf16x8 bt = *(const bf16x8*)&t2nf[(kb * 4 + cb) * 512 + ln * 8];
      acc[cb] = __builtin_amdgcn_mfma_f32_16x16x32_bf16(ah, bh, acc[cb], 0, 0, 0);
      acc[cb] = __builtin_amdgcn_mfma_f32_16x16x32_bf16(ah, bl, acc[cb], 0, 0, 0);
      acc[cb] = __builtin_amdgcn_mfma_f32_16x16x32_bf16(al, bh, acc[cb], 0, 0, 0);
      accP[cb] = __builtin_amdgcn_mfma_f32_16x16x32_bf16(ah, bt, accP[cb], 0, 0, 0);
    }
    v0 = n0; v1 = n1;
  }

  // ---- scores epilogue
  float b1v[4], w2v[4];
  #pragma unroll
  for (int cb = 0; cb < 4; ++cb) {
    const int col = cb * 16 + lr;
    b1v[cb] = b1[col]; w2v[cb] = w2[col];
  }
  const float b2v = b2[0];
  #pragma unroll
  for (int r = 0; r < 4; ++r) {
    float p = 0.f;
    #pragma unroll
    for (int cb = 0; cb < 4; ++cb) {
      const float h = fmaxf(acc[cb][r] + b1v[cb], 0.f);
      p = fmaf(h, w2v[cb], p);
    }
    p += __shfl_xor(p, 1); p += __shfl_xor(p, 2);
    p += __shfl_xor(p, 4); p += __shfl_xor(p, 8);
    if (lr == 0) scores[t0 + wv * 16 + 4 * lq + r] = p + b2v;
  }

  // ---- proj D->A bounce (wave-private LDS) then coalesced 16B stash
  #pragma unroll
  for (int cb = 0; cb < 4; ++cb)
    #pragma unroll
    for (int r = 0; r < 4; ++r) {
      const int idx = (cb >> 1) * 512 + (4 * lq + r + 16 * (lr >> 2)) * 8 +
                      (lr & 3) + 4 * (cb & 1);
      mySf[idx] = f2bf(accP[cb][r]);
    }
  u16* stash = (u16*)(outStash + (size_t)blockIdx.x * 32768);
  #pragma unroll
  for (int kb2 = 0; kb2 < 2; ++kb2)
    *(bf16x8*)&stash[wv * 1024 + kb2 * 512 + ln * 8] =
        *(const bf16x8*)&mySf[kb2 * 512 + ln * 8];
}

// ---------------------------------------------------------------------------
// k_select: stats + exact top-64 radix select.
// pass 0 histogram via wave-ballot aggregation (exponent bins are few ->
// LDS same-address atomic serialization killed); passes 1-3 direct atomics.
// Bin scan: in-wave shfl suffix scan, no barriers, unique picker lane.
// ---------------------------------------------------------------------------
__global__ __launch_bounds__(256) void k_select(
    const float* __restrict__ scores, int* __restrict__ top_idx,
    int* __restrict__ take_k)
{
  __shared__ float sS[N_];
  __shared__ u32 hist[256];
  __shared__ float redf[32];
  __shared__ u32 sPrefix, sRank, sCntA, sCntT;
  __shared__ int candIdx[64];
  __shared__ float candVal[64];
  __shared__ int tieIdx[128];
  const int b = blockIdx.x, tid = threadIdx.x;
  const int wv = tid >> 6, ln = tid & 63;
  const float* s = scores + (size_t)b * N_;

  float sum = 0.f, sq = 0.f;
  for (int i = tid; i < N_; i += 256) {
    const float v = s[i]; sS[i] = v; sum += v; sq = fmaf(v, v, sq);
  }
  #pragma unroll
  for (int off = 32; off > 0; off >>= 1) {
    sum += __shfl_xor(sum, off);
    sq  += __shfl_xor(sq, off);
  }
  if (ln == 0) { redf[wv] = sum; redf[8 + wv] = sq; }
  __syncthreads();
  if (tid == 0) {
    const float tot  = (redf[0] + redf[1]) + (redf[2] + redf[3]);
    const float totq = (redf[8] + redf[9]) + (redf[10] + redf[11]);
    const float mean = tot / (float)N_;
    const float var  = totq / (float)N_ - mean * mean;
    redf[16] = mean + 0.5f * sqrtf(fmaxf(var, 0.f));
  }
  __syncthreads();
  const float thr = redf[16];
  int c = 0;
  for (int i = tid; i < N_; i += 256) c += (sS[i] > thr) ? 1 : 0;
  #pragma unroll
  for (int off = 32; off > 0; off >>= 1) c += __shfl_xor(c, off);
  if (ln == 0) hist[wv] = (u32)c;
  __syncthreads();
  if (tid == 0) {
    const int cnt = (int)(hist[0] + hist[1] + hist[2] + hist[3]);
    take_k[b] = (cnt == 0) ? M_ : (cnt < M_ ? cnt : M_);
  }
  __syncthreads();

  u32 prefix = 0, rank = 64, pmask = 0;
  for (int pass = 0; pass < 4; ++pass) {
    const int shift = 24 - 8 * pass;
    hist[tid] = 0;
    __syncthreads();
    for (int i = tid; i < N_; i += 256) {
      const u32 u = __float_as_uint(sS[i]);
      const u32 key = u ^ ((u32)((int)u >> 31) | 0x80000000u);
      const bool active = (key & pmask) == prefix;
      const int bin = (int)((key >> shift) & 255u);
      if (pass == 0) {
        // wave-aggregated counting: one atomic per distinct bin per wave
        unsigned long long act = __ballot(active);
        while (act) {
          const int leader = (int)__builtin_ctzll(act);
          const int lbin = __shfl(bin, leader);
          const unsigned long long eq = __ballot(active && (bin == lbin));
          if (ln == leader) atomicAdd(&hist[lbin], (u32)__builtin_popcountll(eq));
          act &= ~eq;
        }
      } else {
        if (active) atomicAdd(&hist[bin], 1u);
      }
    }
    __syncthreads();
    if (tid < 64) {
      // lane owns bins [4*tid .. 4*tid+3]; suffix sums + pivot pick, no barriers
      const u32 h0 = hist[4 * tid], h1 = hist[4 * tid + 1];
      const u32 h2 = hist[4 * tid + 2], h3 = hist[4 * tid + 3];
      const u32 s3 = h3, s2 = h2 + s3, s1 = h1 + s2, s0 = h0 + s1;
      u32 run = s0;
      #pragma unroll
      for (int off = 1; off < 64; off <<= 1) {
        const u32 t = (u32)__shfl_down((int)run, off);
        if (tid + off < 64) run += t;
      }
      const u32 excl = run - s0;  // sum over bins >= 4*(tid+1)
      const u32 c0 = s0 + excl, c1 = s1 + excl, c2 = s2 + excl, c3 = s3 + excl;
      int pick = -1; u32 nxt = 0;
      if (c0 >= rank && c1 < rank)        { pick = 0; nxt = c1; }
      else if (c1 >= rank && c2 < rank)   { pick = 1; nxt = c2; }
      else if (c2 >= rank && c3 < rank)   { pick = 2; nxt = c3; }
      else if (c3 >= rank && excl < rank) { pick = 3; nxt = excl; }
      if (pick >= 0) {
        sPrefix = prefix | ((u32)(4 * tid + pick) << shift);
        sRank = rank - nxt;
      }
    }
    __syncthreads();
    prefix = sPrefix; rank = sRank;
    pmask |= 0xFFu << shift;
    __syncthreads();
  }

  if (tid == 0) { sCntA = 0; sCntT = 0; }
  __syncthreads();
  const u32 pivot = prefix;
  for (int i = tid; i < N_; i += 256) {
    const u32 u = __float_as_uint(sS[i]);
    const u32 key = u ^ ((u32)((int)u >> 31) | 0x80000000u);
    if (key > pivot) {
      const u32 p = atomicAdd(&sCntA, 1u);
      candIdx[p] = i; candVal[p] = sS[i];
    } else if (key == pivot) {
      const u32 p = atomicAdd(&sCntT, 1u);
      if (p < 128) tieIdx[p] = i;
    }
  }
  __syncthreads();
  if (tid == 0) {
    const int nA = (int)sCntA;
    const int need = 64 - nA;
    int nT = (int)sCntT; if (nT > 128) nT = 128;
    for (int j = 0; j < need; ++j) {
      int bi = 1 << 30, bp = -1;
      for (int q = 0; q < nT; ++q) {
        const int v = tieIdx[q];
        if (v >= 0 && v < bi) { bi = v; bp = q; }
      }
      candIdx[nA + j] = bi; candVal[nA + j] = sS[bi]; tieIdx[bp] = -1;
    }
  }
  __syncthreads();
  if (tid < 64) {
    const float v = candVal[tid]; const int ii = candIdx[tid];
    int rk = 0;
    for (int j = 0; j < 64; ++j) {
      const float vj = candVal[j]; const int ij = candIdx[j];
      rk += (vj > v || (vj == v && ij < ii)) ? 1 : 0;
    }
    top_idx[b * M_ + rk] = ii;
  }
}

// ---------------------------------------------------------------------------
// fragment loaders from fp32 LDS [64][65]
// ---------------------------------------------------------------------------
__device__ __forceinline__ bf16x8 ldsA_frag(const float (*S)[65], int wv, int kb, int ln) {
  const int lr = ln & 15;
  bf16x8 a;
  #pragma unroll
  for (int e = 0; e < 8; ++e) a[e] = (short)f2bf(S[16 * wv + lr][32 * kb + kslot(ln, e)]);
  return a;
}
__device__ __forceinline__ bf16x8 ldsB_frag(const float (*S)[65], int cb, int kb, int ln) {
  const int lr = ln & 15;
  bf16x8 bb;
  #pragma unroll
  for (int e = 0; e < 8; ++e) bb[e] = (short)f2bf(S[32 * kb + kslot(ln, e)][16 * cb + lr]);
  return bb;
}
__device__ __forceinline__ bf16x8 ldsBT_frag(const float (*S)[65], int cb, int kb, int ln) {
  const int lr = ln & 15;
  bf16x8 bb;
  #pragma unroll
  for (int e = 0; e < 8; ++e) bb[e] = (short)f2bf(S[16 * cb + lr][32 * kb + kslot(ln, e)]);
  return bb;
}

// ---------------------------------------------------------------------------
// k_graph: gather + H0 + cosine adjacency + 2-layer GCN + W = Hg@n2t
// ---------------------------------------------------------------------------
__global__ __launch_bounds__(256) void k_graph(
    const float* __restrict__ X, const u16* __restrict__ t2nf,
    const u16* __restrict__ n2tf, const u16* __restrict__ g1f,
    const u16* __restrict__ g2f, const int* __restrict__ top_idx,
    const int* __restrict__ take_k, u16* __restrict__ HgTf,
    u16* __restrict__ Wf)
{
  __shared__ float sH0[64][65];
  __shared__ float sA[64][65];
  __shared__ float sT[64][65];
  __shared__ float sU[64][65];
  __shared__ float sR[64];
  const int b = blockIdx.x, tid = threadIdx.x;
  const int wv = tid >> 6, ln = tid & 63;
  const int lq = ln >> 4, lr = ln & 15;
  const int tk = take_k[b];
  const int rowm = 16 * wv + 4 * lq;

  // ---- H0 = gather(X) @ t2n (K=512), masked
  const int gidx = top_idx[b * M_ + 16 * wv + lr];
  const float* xr = X + ((size_t)b * N_ + gidx) * D_;
  f32x4 d[4];
  #pragma unroll
  for (int cb = 0; cb < 4; ++cb) d[cb] = (f32x4){0.f, 0.f, 0.f, 0.f};
  for (int kb = 0; kb < 16; ++kb) {
    const float4 v0 = *(const float4*)(xr + 32 * kb + 4 * lq);
    const float4 v1 = *(const float4*)(xr + 32 * kb + 16 + 4 * lq);
    const bf16x8 a = pack8(v0, v1);
    #pragma unroll
    for (int cb = 0; cb < 4; ++cb) {
      const bf16x8 bb = *(const bf16x8*)&t2nf[(kb * 4 + cb) * 512 + ln * 8];
      d[cb] = __builtin_amdgcn_mfma_f32_16x16x32_bf16(a, bb, d[cb], 0, 0, 0);
    }
  }
  #pragma unroll
  for (int cb = 0; cb < 4; ++cb)
    #pragma unroll
    for (int r = 0; r < 4; ++r)
      sH0[rowm + r][16 * cb + lr] = (rowm + r < tk) ? d[cb][r] : 0.f;
  __syncthreads();

  // ---- norms -> inverse
  if (tid < 64) {
    float s = 0.f;
    #pragma unroll
    for (int k = 0; k < 64; ++k) { const float v = sH0[tid][k]; s = fmaf(v, v, s); }
    sR[tid] = 1.f / fmaxf(sqrtf(s), 1e-6f);
  }
  __syncthreads();
  #pragma unroll
  for (int p = 0; p < 16; ++p) {
    const int o = tid + p * 256;
    const int i = o >> 6, k = o & 63;
    sU[i][k] = sH0[i][k] * sR[i];
  }
  __syncthreads();

  // ---- A = relu(Hn @ Hn^T), mask, +diag
  #pragma unroll
  for (int cb = 0; cb < 4; ++cb) d[cb] = (f32x4){0.f, 0.f, 0.f, 0.f};
  #pragma unroll
  for (int kb = 0; kb < 2; ++kb) {
    const bf16x8 a = ldsA_frag(sU, wv, kb, ln);
    #pragma unroll
    for (int cb = 0; cb < 4; ++cb)
      d[cb] = __builtin_amdgcn_mfma_f32_16x16x32_bf16(a, ldsBT_frag(sU, cb, kb, ln), d[cb], 0, 0, 0);
  }
  __syncthreads();
  #pragma unroll
  for (int cb = 0; cb < 4; ++cb)
    #pragma unroll
    for (int r = 0; r < 4; ++r) {
      const int row = rowm + r, col = 16 * cb + lr;
      float s = fmaxf(d[cb][r], 0.f);
      s = (row < tk && col < tk) ? s : 0.f;
      if (row == col && row < tk) s += 1.f;
      sA[row][col] = s;
    }
  __syncthreads();

  // ---- row-normalize A
  if (tid < 64) {
    float rs = 0.f;
    #pragma unroll
    for (int j = 0; j < 64; ++j) rs += sA[tid][j];
    sR[tid] = 1.f / fmaxf(rs, 1e-6f);
  }
  __syncthreads();
  #pragma unroll
  for (int p = 0; p < 16; ++p) {
    const int o = tid + p * 256;
    const int i = o >> 6, j = o & 63;
    sA[i][j] *= sR[i];
  }
  __syncthreads();

  // ---- T = A @ H0
  #pragma unroll
  for (int cb = 0; cb < 4; ++cb) d[cb] = (f32x4){0.f, 0.f, 0.f, 0.f};
  #pragma unroll
  for (int kb = 0; kb < 2; ++kb) {
    const bf16x8 a = ldsA_frag(sA, wv, kb, ln);
    #pragma unroll
    for (int cb = 0; cb < 4; ++cb)
      d[cb] = __builtin_amdgcn_mfma_f32_16x16x32_bf16(a, ldsB_frag(sH0, cb, kb, ln), d[cb], 0, 0, 0);
  }
  __syncthreads();
  #pragma unroll
  for (int cb = 0; cb < 4; ++cb)
    #pragma unroll
    for (int r = 0; r < 4; ++r) sT[rowm + r][16 * cb + lr] = d[cb][r];
  __syncthreads();

  // ---- X1 = relu(T @ g1)
  #pragma unroll
  for (int cb = 0; cb < 4; ++cb) d[cb] = (f32x4){0.f, 0.f, 0.f, 0.f};
  #pragma unroll
  for (int kb = 0; kb < 2; ++kb) {
    const bf16x8 a = ldsA_frag(sT, wv, kb, ln);
    #pragma unroll
    for (int cb = 0; cb < 4; ++cb) {
      const bf16x8 bb = *(const bf16x8*)&g1f[(kb * 4 + cb) * 512 + ln * 8];
      d[cb] = __builtin_amdgcn_mfma_f32_16x16x32_bf16(a, bb, d[cb], 0, 0, 0);
    }
  }
  __syncthreads();
  #pragma unroll
  for (int cb = 0; cb < 4; ++cb)
    #pragma unroll
    for (int r = 0; r < 4; ++r) sU[rowm + r][16 * cb + lr] = fmaxf(d[cb][r], 0.f);
  __syncthreads();

  // ---- T2 = A @ X1
  #pragma unroll
  for (int cb = 0; cb < 4; ++cb) d[cb] = (f32x4){0.f, 0.f, 0.f, 0.f};
  #pragma unroll
  for (int kb = 0; kb < 2; ++kb) {
    const bf16x8 a = ldsA_frag(sA, wv, kb, ln);
    #pragma unroll
    for (int cb = 0; cb < 4; ++cb)
      d[cb] = __builtin_amdgcn_mfma_f32_16x16x32_bf16(a, ldsB_frag(sU, cb, kb, ln), d[cb], 0, 0, 0);
  }
  __syncthreads();
  #pragma unroll
  for (int cb = 0; cb < 4; ++cb)
    #pragma unroll
    for (int r = 0; r < 4; ++r) sT[rowm + r][16 * cb + lr] = d[cb][r];
  __syncthreads();

  // ---- Hg = relu(T2 @ g2) -> HgTf frags + LDS (for W matmul)
  #pragma unroll
  for (int cb = 0; cb < 4; ++cb) d[cb] = (f32x4){0.f, 0.f, 0.f, 0.f};
  #pragma unroll
  for (int kb = 0; kb < 2; ++kb) {
    const bf16x8 a = ldsA_frag(sT, wv, kb, ln);
    #pragma unroll
    for (int cb = 0; cb < 4; ++cb) {
      const bf16x8 bb = *(const bf16x8*)&g2f[(kb * 4 + cb) * 512 + ln * 8];
      d[cb] = __builtin_amdgcn_mfma_f32_16x16x32_bf16(a, bb, d[cb], 0, 0, 0);
    }
  }
  __syncthreads();
  #pragma unroll
  for (int cb = 0; cb < 4; ++cb)
    #pragma unroll
    for (int r = 0; r < 4; ++r) {
      const int node = rowm + r, feat = 16 * cb + lr;
      const float hv = fmaxf(d[cb][r], 0.f);
      HgTf[(size_t)b * 4096 + bfrag_idx(feat, node, 4)] = f2bf(hv);
      sU[node][feat] = hv;
    }
  __syncthreads();

  // ---- W = Hg @ n2t  [m=64][d=512] -> Wf B-frags (kd = m)
  for (int chk = 0; chk < 4; ++chk) {
    f32x4 aw[8];
    #pragma unroll
    for (int c8 = 0; c8 < 8; ++c8) aw[c8] = (f32x4){0.f, 0.f, 0.f, 0.f};
    #pragma unroll
    for (int kbf = 0; kbf < 2; ++kbf) {
      const bf16x8 a = ldsA_frag(sU, wv, kbf, ln);
      #pragma unroll
      for (int c8 = 0; c8 < 8; ++c8) {
        const bf16x8 bb = *(const bf16x8*)&n2tf[(kbf * 32 + chk * 8 + c8) * 512 + ln * 8];
        aw[c8] = __builtin_amdgcn_mfma_f32_16x16x32_bf16(a, bb, aw[c8], 0, 0, 0);
      }
    }
    #pragma unroll
    for (int c8 = 0; c8 < 8; ++c8)
      #pragma unroll
      for (int r = 0; r < 4; ++r) {
        const int m = 16 * wv + 4 * lq + r;
        const int c = (chk * 8 + c8) * 16 + lr;
        Wf[(size_t)b * 32768 + bfrag_idx(m, c, 32)] = f2bf(aw[c8][r]);
      }
  }
}

// ---------------------------------------------------------------------------
// k_attn: logits(from stashed proj frags)->softmax->back(attn@W)->residual
// ---------------------------------------------------------------------------
__global__ __launch_bounds__(256) void k_attn(
    const float* __restrict__ X, const u16* __restrict__ HgTf,
    const u16* __restrict__ Wf, float* __restrict__ out)
{
  __shared__ __align__(16) u16 sAf[4096];  // 4 waves x 1KB wave-private
  const int tid = threadIdx.x;
  const int b = blockIdx.x >> 7;
  const int t0 = (blockIdx.x & 127) << 6;
  const float* Xb = X + (size_t)b * N_ * D_;
  float* Ob = out + (size_t)b * N_ * D_;
  const int wv = tid >> 6, ln = tid & 63;
  const int lq = ln >> 4, lr = ln & 15;
  u16* mySf = &sAf[wv * 1024];
  const u16* stash = (const u16*)(out + (size_t)blockIdx.x * 32768);

  // ---- P2: logits = proj @ Hg^T (K=64); proj A-frags read from stash
  f32x4 accL[4];
  #pragma unroll
  for (int cb = 0; cb < 4; ++cb) accL[cb] = (f32x4){0.f, 0.f, 0.f, 0.f};
  #pragma unroll
  for (int kb = 0; kb < 2; ++kb) {
    const bf16x8 a = *(const bf16x8*)&stash[wv * 1024 + kb * 512 + ln * 8];
    #pragma unroll
    for (int cb = 0; cb < 4; ++cb) {
      const bf16x8 bb = *(const bf16x8*)&HgTf[(size_t)b * 4096 + (kb * 4 + cb) * 512 + ln * 8];
      accL[cb] = __builtin_amdgcn_mfma_f32_16x16x32_bf16(a, bb, accL[cb], 0, 0, 0);
    }
  }

  // ---- P3: softmax over m in registers
  float attnv[4][4];
  #pragma unroll
  for (int r = 0; r < 4; ++r) {
    const float v0 = accL[0][r], v1 = accL[1][r], v2 = accL[2][r], v3 = accL[3][r];
    float mx = fmaxf(fmaxf(v0, v1), fmaxf(v2, v3));
    mx = fmaxf(mx, __shfl_xor(mx, 1)); mx = fmaxf(mx, __shfl_xor(mx, 2));
    mx = fmaxf(mx, __shfl_xor(mx, 4)); mx = fmaxf(mx, __shfl_xor(mx, 8));
    const float e0 = __expf((v0 - mx) * 0.125f), e1 = __expf((v1 - mx) * 0.125f);
    const float e2 = __expf((v2 - mx) * 0.125f), e3 = __expf((v3 - mx) * 0.125f);
    float sm = (e0 + e1) + (e2 + e3);
    sm += __shfl_xor(sm, 1); sm += __shfl_xor(sm, 2);
    sm += __shfl_xor(sm, 4); sm += __shfl_xor(sm, 8);
    const float inv = 1.f / sm;
    attnv[0][r] = e0 * inv; attnv[1][r] = e1 * inv;
    attnv[2][r] = e2 * inv; attnv[3][r] = e3 * inv;
  }
  // attn D->A bounce, wave-private
  #pragma unroll
  for (int cb = 0; cb < 4; ++cb)
    #pragma unroll
    for (int r = 0; r < 4; ++r) {
      const int idx = (cb >> 1) * 512 + (4 * lq + r + 16 * (lr >> 2)) * 8 +
                      (lr & 3) + 4 * (cb & 1);
      mySf[idx] = f2bf(attnv[cb][r]);
    }

  // ---- P7: back = attn @ W (K=64, W = Hg@n2t) + residual stream
  for (int chk = 0; chk < 4; ++chk) {
    f32x4 accB[8];
    #pragma unroll
    for (int c8 = 0; c8 < 8; ++c8) accB[c8] = (f32x4){0.f, 0.f, 0.f, 0.f};
    #pragma unroll
    for (int kb = 0; kb < 2; ++kb) {
      const bf16x8 a = *(const bf16x8*)&mySf[kb * 512 + ln * 8];
      #pragma unroll
      for (int c8 = 0; c8 < 8; ++c8) {
        const bf16x8 bb = *(const bf16x8*)&Wf[(size_t)b * 32768 + (kb * 32 + chk * 8 + c8) * 512 + ln * 8];
        accB[c8] = __builtin_amdgcn_mfma_f32_16x16x32_bf16(a, bb, accB[c8], 0, 0, 0);
      }
    }
    #pragma unroll
    for (int c8 = 0; c8 < 8; ++c8)
      #pragma unroll
      for (int r = 0; r < 4; ++r) {
        const int row = t0 + 16 * wv + 4 * lq + r;
        const int col = chk * 128 + 16 * c8 + lr;
        const size_t off = (size_t)row * D_ + col;
        Ob[off] = Xb[off] + accB[c8][r];
      }
  }
}

// ---------------------------------------------------------------------------
extern "C" void kernel_launch(void* const* d_in, const int* in_sizes, int n_in,
                              void* d_out, int out_size, void* d_ws, size_t ws_size,
                              hipStream_t stream)
{
  (void)in_sizes; (void)n_in; (void)out_size; (void)ws_size;
  const float* X   = (const float*)d_in[0];
  const float* W1  = (const float*)d_in[1];
  const float* b1  = (const float*)d_in[2];
  const float* w2  = (const float*)d_in[3];
  const float* b2  = (const float*)d_in[4];
  const float* t2n = (const float*)d_in[5];
  const float* n2t = (const float*)d_in[6];
  const float* g1  = (const float*)d_in[7];
  const float* g2  = (const float*)d_in[8];
  float* out = (float*)d_out;

  char* ws = (char*)d_ws;
  float* scores = (float*)(ws);                  // 256 KB
  u16* t2nf     = (u16*)(ws + 262144);           // 64 KB
  u16* n2tf     = (u16*)(ws + 327680);           // 64 KB
  u16* W1h      = (u16*)(ws + 393216);           // 64 KB
  u16* W1l      = (u16*)(ws + 458752);           // 64 KB
  u16* HgTf     = (u16*)(ws + 524288);           // 64 KB
  u16* g1f      = (u16*)(ws + 589824);           // 8 KB
  u16* g2f      = (u16*)(ws + 598016);           // 8 KB
  int* top_idx  = (int*)(ws + 606208);           // 2 KB
  int* take_k   = (int*)(ws + 608256);           // 32 B
  u16* Wf       = (u16*)(ws + 609280);           // 512 KB

  k_prep<<<64, 256, 0, stream>>>(t2n, n2t, W1, g1, g2, t2nf, n2tf, W1h, W1l, g1f, g2f);
  k_sp<<<1024, 256, 0, stream>>>(X, W1h, W1l, t2nf, b1, w2, b2, scores, out);
  k_select<<<B_, 256, 0, stream>>>(scores, top_idx, take_k);
  k_graph<<<B_, 256, 0, stream>>>(X, t2nf, n2tf, g1f, g2f, top_idx, take_k, HgTf, Wf);
  k_attn<<<1024, 256, 0, stream>>>(X, HgTf, Wf, out);
}